// Round 1
// baseline (3478.733 us; speedup 1.0000x reference)
//
#include <hip/hip_runtime.h>

typedef unsigned short u16;
typedef unsigned int u32;
typedef __attribute__((ext_vector_type(8))) short bf16x8;
typedef __attribute__((ext_vector_type(4))) float f32x4;

#define BN_EPS 1e-5f

__device__ __forceinline__ float bf2f(u16 u) {
  union { unsigned u; float f; } x; x.u = ((unsigned)u) << 16; return x.f;
}
__device__ __forceinline__ u16 f2bf(float f) {
  union { float f; unsigned u; } x; x.f = f;
  unsigned r = x.u + 0x7FFFu + ((x.u >> 16) & 1u);
  return (u16)(r >> 16);
}

// ---------------- conv 3x3 stride2 pad1, NCHW/OIHW, fp32 ----------------
__global__ void conv3x3s2(const float* __restrict__ in, const float* __restrict__ w,
                          const float* __restrict__ bias, float* __restrict__ out,
                          int N, int Ci, int Hi, int Wi, int Co, int Ho, int Wo) {
  int idx = blockIdx.x * blockDim.x + threadIdx.x;
  int total = N * Co * Ho * Wo;
  if (idx >= total) return;
  int wo = idx % Wo; int t = idx / Wo;
  int ho = t % Ho; t /= Ho;
  int co = t % Co; int n = t / Co;
  int hi0 = ho * 2 - 1, wi0 = wo * 2 - 1;
  float acc = bias[co];
  const float* wp = w + (size_t)co * Ci * 9;
  for (int ci = 0; ci < Ci; ci++) {
    const float* ip = in + ((size_t)(n * Ci + ci) * Hi) * Wi;
    const float* wc = wp + ci * 9;
#pragma unroll
    for (int kh = 0; kh < 3; kh++) {
      int hi = hi0 + kh;
      if (hi < 0 || hi >= Hi) continue;
#pragma unroll
      for (int kw = 0; kw < 3; kw++) {
        int wi = wi0 + kw;
        if (wi < 0 || wi >= Wi) continue;
        acc += ip[hi * Wi + wi] * wc[kh * 3 + kw];
      }
    }
  }
  out[idx] = acc;
}

// ---------------- batchnorm (training stats) ----------------
__global__ void bn_stats(const float* __restrict__ x, const float* __restrict__ gamma,
                         const float* __restrict__ beta, float* __restrict__ ss,
                         int N, int C, int HW) {
  int c = blockIdx.x;
  int t = threadIdx.x;
  float s1 = 0.f, s2 = 0.f;
  for (int n = 0; n < N; n++) {
    const float* p = x + (size_t)(n * C + c) * HW;
    for (int i = t; i < HW; i += 256) { float v = p[i]; s1 += v; s2 += v * v; }
  }
  __shared__ float l1[256], l2[256];
  l1[t] = s1; l2[t] = s2; __syncthreads();
  for (int off = 128; off > 0; off >>= 1) {
    if (t < off) { l1[t] += l1[t + off]; l2[t] += l2[t + off]; }
    __syncthreads();
  }
  if (t == 0) {
    float M = (float)N * (float)HW;
    float mu = l1[0] / M;
    float var = l2[0] / M - mu * mu;
    float sc = gamma[c] * rsqrtf(var + BN_EPS);
    ss[c] = sc; ss[C + c] = beta[c] - mu * sc;
  }
}

__global__ void bn_relu(float* __restrict__ x, const float* __restrict__ ss,
                        int total, int C, int HW) {
  int idx = blockIdx.x * blockDim.x + threadIdx.x;
  if (idx >= total) return;
  int c = (idx / HW) % C;
  float v = x[idx] * ss[c] + ss[C + c];
  x[idx] = v > 0.f ? v : 0.f;
}

// ---------------- obj pack: y4 [64,256,25] -> obj bf16 [1664 rows][256] ----------------
__global__ void obj_pack(const float* __restrict__ y4, u16* __restrict__ obj) {
  int idx = blockIdx.x * blockDim.x + threadIdx.x;
  if (idx >= 1664 * 256) return;
  int c = idx & 255; int row = idx >> 8;
  float v = 0.f;
  if (row < 1600) {
    int b = row / 25, p = row % 25;
    v = y4[((size_t)(b * 256 + c) * 25) + p];
  }
  obj[idx] = f2bf(v);
}

// ---------------- weight packs ----------------
__global__ void pack_w1(const float* __restrict__ gw1, u16* __restrict__ W1a, u16* __restrict__ W1b) {
  int idx = blockIdx.x * blockDim.x + threadIdx.x;
  if (idx >= 2048 * 256) return;
  int k = idx & 255, n = idx >> 8;
  float a = 0.f, b = 0.f;
  if (n < 2000) { a = gw1[(size_t)n * 523 + k]; b = gw1[(size_t)n * 523 + 256 + k]; }
  W1a[idx] = f2bf(a); W1b[idx] = f2bf(b);
}

__global__ void pack_wbig(const float* __restrict__ gw, u16* __restrict__ Wp) {
  int idx = blockIdx.x * blockDim.x + threadIdx.x;
  if (idx >= 2048 * 2048) return;
  int k = idx & 2047, n = idx >> 11;
  float v = (n < 2000 && k < 2000) ? gw[(size_t)n * 2000 + k] : 0.f;
  Wp[idx] = f2bf(v);
}

__global__ void pack_bias(const float* __restrict__ b2, const float* __restrict__ b3,
                          const float* __restrict__ b4, float* __restrict__ bp) {
  int i = blockIdx.x * blockDim.x + threadIdx.x;
  if (i >= 2048) return;
  bp[i]        = (i < 2000) ? b2[i] : 0.f;
  bp[2048 + i] = (i < 2000) ? b3[i] : 0.f;
  bp[4096 + i] = (i < 2000) ? b4[i] : 0.f;
}

// ---------------- Q[b][o] = gb1[o] + qst[b] . gw1[o][512:523] ----------------
__global__ void q_build(const float* __restrict__ qst, const float* __restrict__ gw1,
                        const float* __restrict__ gb1, float* __restrict__ Q) {
  int idx = blockIdx.x * blockDim.x + threadIdx.x;
  if (idx >= 64 * 2048) return;
  int o = idx & 2047, b = idx >> 11;
  float v = 0.f;
  if (o < 2000) {
    v = gb1[o];
    const float* w = gw1 + (size_t)o * 523 + 512;
    const float* q = qst + b * 11;
#pragma unroll
    for (int k = 0; k < 11; k++) v += q[k] * w[k];
  }
  Q[idx] = v;
}

// ---------------- bf16 MFMA GEMM: C[m][n] = sum_k A[m][k]*W[n][k] ----------------
// 128x128 tile, BK=32, 4 waves (2x2), fragment-ordered LDS, 16B global_load_lds.
typedef const __attribute__((address_space(1))) u32* gas1;
typedef __attribute__((address_space(3))) u32* las3;
__device__ __forceinline__ void gld16(const void* g, void* l) {
  __builtin_amdgcn_global_load_lds((gas1)g, (las3)l, 16, 0, 0);
}

template <int EPI>  // 0: fp32 store; 1: bf16 store relu(acc+bias[col])
__global__ __launch_bounds__(256) void gemm_bt(
    const u16* __restrict__ A, int lda,
    const u16* __restrict__ W, int ldb,
    float* __restrict__ Cf, u16* __restrict__ Cb, int ldc,
    const float* __restrict__ bias, int KT, int NTN) {
  __shared__ __align__(16) char lds[32768];  // 2 bufs x (A 8K | W 8K)
  int bid = blockIdx.x;
  int cpx = gridDim.x >> 3;                 // grid % 8 == 0 by construction
  int wg = (bid & 7) * cpx + (bid >> 3);    // XCD-aware swizzle
  int mt = wg / NTN, nt = wg % NTN;
  int tid = threadIdx.x;
  int wave = tid >> 6, lane = tid & 63;
  int r = lane & 15, g = lane >> 4;
  int wr = wave >> 1, wc = wave & 1;

  // wave stages A sub-tiles {2w,2w+1} (rows wave*32..wave*32+31), same for W
  const u16* Asrc = A + (size_t)(mt * 128 + wave * 32 + r) * lda + g * 8;
  const u16* Wsrc = W + (size_t)(nt * 128 + wave * 32 + r) * ldb + g * 8;

  f32x4 acc[4][4];
#pragma unroll
  for (int i = 0; i < 4; i++)
#pragma unroll
    for (int j = 0; j < 4; j++) acc[i][j] = (f32x4){0.f, 0.f, 0.f, 0.f};

  {  // stage kt=0 into buf0
    char* Al = lds; char* Wl = lds + 8192;
    gld16(Asrc, Al + wave * 2048);
    gld16(Asrc + (size_t)16 * lda, Al + wave * 2048 + 1024);
    gld16(Wsrc, Wl + wave * 2048);
    gld16(Wsrc + (size_t)16 * ldb, Wl + wave * 2048 + 1024);
  }
  __syncthreads();

  int buf = 0;
  for (int kt = 0; kt < KT; kt++) {
    if (kt + 1 < KT) {
      int k0 = (kt + 1) * 32;
      char* Al = lds + (buf ^ 1) * 16384; char* Wl = Al + 8192;
      gld16(Asrc + k0, Al + wave * 2048);
      gld16(Asrc + k0 + (size_t)16 * lda, Al + wave * 2048 + 1024);
      gld16(Wsrc + k0, Wl + wave * 2048);
      gld16(Wsrc + k0 + (size_t)16 * ldb, Wl + wave * 2048 + 1024);
    }
    char* Al = lds + buf * 16384; char* Wl = Al + 8192;
    bf16x8 a[4], w[4];
#pragma unroll
    for (int i = 0; i < 4; i++) a[i] = *(const bf16x8*)(Al + (wr * 4 + i) * 1024 + lane * 16);
#pragma unroll
    for (int j = 0; j < 4; j++) w[j] = *(const bf16x8*)(Wl + (wc * 4 + j) * 1024 + lane * 16);
#pragma unroll
    for (int i = 0; i < 4; i++)
#pragma unroll
      for (int j = 0; j < 4; j++)
        acc[i][j] = __builtin_amdgcn_mfma_f32_16x16x32_bf16(a[i], w[j], acc[i][j], 0, 0, 0);
    __syncthreads();
    buf ^= 1;
  }

  // epilogue: D layout col=lane&15, row=(lane>>4)*4+q
  int rowb = mt * 128 + wr * 64 + (lane >> 4) * 4;
  int colb = nt * 128 + wc * 64 + (lane & 15);
#pragma unroll
  for (int i = 0; i < 4; i++) {
#pragma unroll
    for (int j = 0; j < 4; j++) {
      int col = colb + j * 16;
      float bv = (EPI == 1) ? bias[col] : 0.f;
#pragma unroll
      for (int q = 0; q < 4; q++) {
        int row = rowb + i * 16 + q;
        float v = acc[i][j][q];
        if (EPI == 1) {
          v += bv; v = v > 0.f ? v : 0.f;
          Cb[(size_t)row * ldc + col] = f2bf(v);
        } else {
          Cf[(size_t)row * ldc + col] = v;
        }
      }
    }
  }
}

// ---------------- h1 = relu(A_i + B_j + Q_b), bf16, padded rows zero ----------------
__global__ void h1_build(const float* __restrict__ Afull, const float* __restrict__ Bfull,
                         const float* __restrict__ Q, u16* __restrict__ h1,
                         int c0, int nrows) {
  int row = blockIdx.x;
  int t = threadIdx.x;
  u16* dst = h1 + (size_t)row * 2048;
  if (row >= nrows) {
#pragma unroll
    for (int it = 0; it < 2; it++) {
      int o = it * 1024 + t * 4;
      ushort4 z; z.x = 0; z.y = 0; z.z = 0; z.w = 0;
      *(ushort4*)(dst + o) = z;
    }
    return;
  }
  int b_local = row / 625; int rem = row % 625;
  int i = rem / 25, j = rem % 25;
  int b = c0 + b_local;
  const float* Ap = Afull + (size_t)(b * 25 + i) * 2048;
  const float* Bp = Bfull + (size_t)(b * 25 + j) * 2048;
  const float* Qp = Q + (size_t)b * 2048;
#pragma unroll
  for (int it = 0; it < 2; it++) {
    int o = it * 1024 + t * 4;
    float4 av = *(const float4*)(Ap + o);
    float4 bv = *(const float4*)(Bp + o);
    float4 qv = *(const float4*)(Qp + o);
    ushort4 outv;
    float v;
    v = av.x + bv.x + qv.x; outv.x = f2bf(v > 0.f ? v : 0.f);
    v = av.y + bv.y + qv.y; outv.y = f2bf(v > 0.f ? v : 0.f);
    v = av.z + bv.z + qv.z; outv.z = f2bf(v > 0.f ? v : 0.f);
    v = av.w + bv.w + qv.w; outv.w = f2bf(v > 0.f ? v : 0.f);
    *(ushort4*)(dst + o) = outv;
  }
}

// ---------------- xg[b][o] += sum_p h4[b_local*625+p][o] ----------------
__global__ void reduce_xg(const u16* __restrict__ h4, float* __restrict__ xg, int c0) {
  int o = blockIdx.x * blockDim.x + threadIdx.x;  // 0..2047
  int b_local = blockIdx.y;
  const u16* p = h4 + (size_t)b_local * 625 * 2048 + o;
  float s = 0.f;
  for (int k = 0; k < 625; k++) s += bf2f(p[(size_t)k * 2048]);
  xg[(size_t)(c0 + b_local) * 2048 + o] += s;
}

__global__ void zero_xg(float* __restrict__ xg) {
  int i = blockIdx.x * blockDim.x + threadIdx.x;
  if (i < 64 * 2048) xg[i] = 0.f;
}

// ---------------- f MLP: warp per output, fp32 ----------------
__global__ void f_layer(const float* __restrict__ x, int ldx, int Kin,
                        const float* __restrict__ Wf, const float* __restrict__ bf_,
                        float* __restrict__ y, int ldy, int Nout, float scale, int relu) {
  int gwid = (blockIdx.x * blockDim.x + threadIdx.x) >> 6;
  int lane = threadIdx.x & 63;
  if (gwid >= 64 * Nout) return;
  int b = gwid / Nout, o = gwid % Nout;
  const float* xp = x + (size_t)b * ldx;
  const float* wp = Wf + (size_t)o * Kin;
  float s = 0.f;
  for (int k = lane; k < Kin; k += 64) s += xp[k] * wp[k];
  for (int off = 32; off > 0; off >>= 1) s += __shfl_down(s, off);
  if (lane == 0) {
    float v = s * scale + bf_[o];
    if (relu) v = v > 0.f ? v : 0.f;
    y[(size_t)b * ldy + o] = v;
  }
}

__global__ void lsm_kernel(const float* __restrict__ xf4, float* __restrict__ out) {
  int b = blockIdx.x * blockDim.x + threadIdx.x;
  if (b >= 64) return;
  const float* x = xf4 + b * 16;
  float m = x[0];
  for (int i = 1; i < 10; i++) m = fmaxf(m, x[i]);
  float s = 0.f;
  for (int i = 0; i < 10; i++) s += expf(x[i] - m);
  float ls = logf(s);
  for (int i = 0; i < 10; i++) out[b * 10 + i] = x[i] - m - ls;
}

// ---------------- host ----------------
extern "C" void kernel_launch(void* const* d_in, const int* in_sizes, int n_in,
                              void* d_out, int out_size, void* d_ws, size_t ws_size,
                              hipStream_t stream) {
  const float* img = (const float*)d_in[0];
  const float* qst = (const float*)d_in[1];
  const float* w1 = (const float*)d_in[2];  const float* b1 = (const float*)d_in[3];
  const float* w2 = (const float*)d_in[4];  const float* b2 = (const float*)d_in[5];
  const float* w3 = (const float*)d_in[6];  const float* b3 = (const float*)d_in[7];
  const float* w4 = (const float*)d_in[8];  const float* b4 = (const float*)d_in[9];
  const float* g1 = (const float*)d_in[10]; const float* be1 = (const float*)d_in[11];
  const float* g2 = (const float*)d_in[12]; const float* be2 = (const float*)d_in[13];
  const float* g3 = (const float*)d_in[14]; const float* be3 = (const float*)d_in[15];
  const float* g4 = (const float*)d_in[16]; const float* be4 = (const float*)d_in[17];
  const float* gw1 = (const float*)d_in[18]; const float* gb1 = (const float*)d_in[19];
  const float* gw2 = (const float*)d_in[20]; const float* gb2 = (const float*)d_in[21];
  const float* gw3 = (const float*)d_in[22]; const float* gb3 = (const float*)d_in[23];
  const float* gw4 = (const float*)d_in[24]; const float* gb4 = (const float*)d_in[25];
  const float* fw1 = (const float*)d_in[26]; const float* fb1 = (const float*)d_in[27];
  const float* fw2 = (const float*)d_in[28]; const float* fb2 = (const float*)d_in[29];
  const float* fw3 = (const float*)d_in[30]; const float* fb3 = (const float*)d_in[31];
  const float* fw4 = (const float*)d_in[32]; const float* fb4 = (const float*)d_in[33];
  float* out = (float*)d_out;

  char* p = (char*)d_ws;
  auto alloc = [&](size_t bytes) -> char* {
    char* r = p; p += (bytes + 255) & ~(size_t)255; return r;
  };
  float* y1 = (float*)alloc(2957312ull * 4);
  float* y2 = (float*)alloc(1478656ull * 4);
  float* y3 = (float*)alloc(819200ull * 4);
  float* y4 = (float*)alloc(409600ull * 4);
  float* ss = (float*)alloc(512 * 4);
  u16* obj = (u16*)alloc(1664ull * 256 * 2);
  u16* W1a = (u16*)alloc(2048ull * 256 * 2);
  u16* W1b = (u16*)alloc(2048ull * 256 * 2);
  u16* Wp2 = (u16*)alloc(2048ull * 2048 * 2);
  u16* Wp3 = (u16*)alloc(2048ull * 2048 * 2);
  u16* Wp4 = (u16*)alloc(2048ull * 2048 * 2);
  float* bp = (float*)alloc(3ull * 2048 * 4);
  float* Q = (float*)alloc(64ull * 2048 * 4);
  float* Afull = (float*)alloc(1664ull * 2048 * 4);
  float* Bfull = (float*)alloc(1664ull * 2048 * 4);
  float* xg = (float*)alloc(64ull * 2048 * 4);
  float* xf1 = (float*)alloc(64ull * 1024 * 4);
  float* xf2 = (float*)alloc(64ull * 512 * 4);
  float* xf3 = (float*)alloc(64ull * 128 * 4);
  float* xf4 = (float*)alloc(64ull * 16 * 4);

  // pick largest image-chunk whose ping-pong h-buffers fit the workspace
  size_t fixed_end = (size_t)(p - (char*)d_ws);
  int cands[7] = {64, 32, 16, 8, 4, 2, 1};
  int CHI = 1;
  size_t Mp = ((1ull * 625 + 127) / 128) * 128;
  for (int ci = 0; ci < 7; ci++) {
    size_t mp = (((size_t)cands[ci] * 625 + 127) / 128) * 128;
    size_t hb = (mp * 2048 * 2 + 255) & ~(size_t)255;
    if (fixed_end + 2 * hb <= ws_size) { CHI = cands[ci]; Mp = mp; break; }
  }
  u16* h0 = (u16*)alloc(Mp * 2048 * 2);
  u16* h1b = (u16*)alloc(Mp * 2048 * 2);

  // ---- conv stack ----
  conv3x3s2<<<(2957312 + 255) / 256, 256, 0, stream>>>(img, w1, b1, y1, 64, 3, 75, 75, 32, 38, 38);
  bn_stats<<<32, 256, 0, stream>>>(y1, g1, be1, ss, 64, 32, 1444);
  bn_relu<<<(2957312 + 255) / 256, 256, 0, stream>>>(y1, ss, 2957312, 32, 1444);

  conv3x3s2<<<(1478656 + 255) / 256, 256, 0, stream>>>(y1, w2, b2, y2, 64, 32, 38, 38, 64, 19, 19);
  bn_stats<<<64, 256, 0, stream>>>(y2, g2, be2, ss, 64, 64, 361);
  bn_relu<<<(1478656 + 255) / 256, 256, 0, stream>>>(y2, ss, 1478656, 64, 361);

  conv3x3s2<<<(819200 + 255) / 256, 256, 0, stream>>>(y2, w3, b3, y3, 64, 64, 19, 19, 128, 10, 10);
  bn_stats<<<128, 256, 0, stream>>>(y3, g3, be3, ss, 64, 128, 100);
  bn_relu<<<(819200 + 255) / 256, 256, 0, stream>>>(y3, ss, 819200, 128, 100);

  conv3x3s2<<<(409600 + 255) / 256, 256, 0, stream>>>(y3, w4, b4, y4, 64, 128, 10, 10, 256, 5, 5);
  bn_stats<<<256, 256, 0, stream>>>(y4, g4, be4, ss, 64, 256, 25);
  bn_relu<<<(409600 + 255) / 256, 256, 0, stream>>>(y4, ss, 409600, 256, 25);

  // ---- packs ----
  obj_pack<<<1664, 256, 0, stream>>>(y4, obj);
  pack_w1<<<2048, 256, 0, stream>>>(gw1, W1a, W1b);
  pack_wbig<<<16384, 256, 0, stream>>>(gw2, Wp2);
  pack_wbig<<<16384, 256, 0, stream>>>(gw3, Wp3);
  pack_wbig<<<16384, 256, 0, stream>>>(gw4, Wp4);
  pack_bias<<<8, 256, 0, stream>>>(gb2, gb3, gb4, bp);
  q_build<<<512, 256, 0, stream>>>(qst, gw1, gb1, Q);

  // ---- layer-1 decomposition GEMMs: A = obj @ W1a^T, B = obj @ W1b^T ----
  gemm_bt<0><<<13 * 16, 256, 0, stream>>>(obj, 256, W1a, 256, Afull, nullptr, 2048, nullptr, 8, 16);
  gemm_bt<0><<<13 * 16, 256, 0, stream>>>(obj, 256, W1b, 256, Bfull, nullptr, 2048, nullptr, 8, 16);

  zero_xg<<<512, 256, 0, stream>>>(xg);

  // ---- chunked g-MLP ----
  int NC = 64 / CHI;
  int mtiles = (int)(Mp / 128);
  for (int c = 0; c < NC; c++) {
    int c0 = c * CHI;
    int nrows = CHI * 625;
    h1_build<<<(unsigned)Mp, 256, 0, stream>>>(Afull, Bfull, Q, h0, c0, nrows);
    gemm_bt<1><<<mtiles * 16, 256, 0, stream>>>(h0, 2048, Wp2, 2048, nullptr, h1b, 2048, bp, 64, 16);
    gemm_bt<1><<<mtiles * 16, 256, 0, stream>>>(h1b, 2048, Wp3, 2048, nullptr, h0, 2048, bp + 2048, 64, 16);
    gemm_bt<1><<<mtiles * 16, 256, 0, stream>>>(h0, 2048, Wp4, 2048, nullptr, h1b, 2048, bp + 4096, 64, 16);
    reduce_xg<<<dim3(8, CHI), 256, 0, stream>>>(h1b, xg, c0);
  }

  // ---- f MLP ----
  {
    int nw, nthreads;
    nw = 64 * 1000; nthreads = nw * 64;
    f_layer<<<(nthreads + 255) / 256, 256, 0, stream>>>(xg, 2048, 2000, fw1, fb1, xf1, 1024, 1000, 1.f / 625.f, 1);
    nw = 64 * 500; nthreads = nw * 64;
    f_layer<<<(nthreads + 255) / 256, 256, 0, stream>>>(xf1, 1024, 1000, fw2, fb2, xf2, 512, 500, 1.f, 1);
    nw = 64 * 100; nthreads = nw * 64;
    f_layer<<<(nthreads + 255) / 256, 256, 0, stream>>>(xf2, 512, 500, fw3, fb3, xf3, 128, 100, 1.f, 1);
    nw = 64 * 10; nthreads = nw * 64;
    f_layer<<<(nthreads + 255) / 256, 256, 0, stream>>>(xf3, 128, 100, fw4, fb4, xf4, 16, 10, 1.f, 0);
  }
  lsm_kernel<<<1, 64, 0, stream>>>(xf4, out);
}

// Round 2
// 2391.423 us; speedup vs baseline: 1.4547x; 1.4547x over previous
//
#include <hip/hip_runtime.h>

typedef unsigned short u16;
typedef unsigned int u32;
typedef __attribute__((ext_vector_type(8))) short bf16x8;
typedef __attribute__((ext_vector_type(4))) float f32x4;

#define BN_EPS 1e-5f
#define BN_S 16

__device__ __forceinline__ float bf2f(u16 u) {
  union { unsigned u; float f; } x; x.u = ((unsigned)u) << 16; return x.f;
}
__device__ __forceinline__ u16 f2bf(float f) {
  union { float f; unsigned u; } x; x.f = f;
  unsigned r = x.u + 0x7FFFu + ((x.u >> 16) & 1u);
  return (u16)(r >> 16);
}

// ---------------- conv1: direct, NHWC output [64*38*38][32] fp32 ----------------
__global__ void conv1_nhwc(const float* __restrict__ img, const float* __restrict__ w,
                           const float* __restrict__ b, float* __restrict__ C1) {
  int idx = blockIdx.x * blockDim.x + threadIdx.x;
  if (idx >= 92416 * 32) return;
  int co = idx & 31; int row = idx >> 5;
  int wo = row % 38; int t = row / 38;
  int ho = t % 38; int n = t / 38;
  int hi0 = ho * 2 - 1, wi0 = wo * 2 - 1;
  float acc = b[co];
  const float* wp = w + co * 27;
#pragma unroll
  for (int ci = 0; ci < 3; ci++) {
    const float* ip = img + ((size_t)(n * 3 + ci) * 75) * 75;
    const float* wc = wp + ci * 9;
#pragma unroll
    for (int kh = 0; kh < 3; kh++) {
      int hi = hi0 + kh;
      if (hi < 0 || hi >= 75) continue;
#pragma unroll
      for (int kw = 0; kw < 3; kw++) {
        int wi = wi0 + kw;
        if (wi < 0 || wi >= 75) continue;
        acc += ip[hi * 75 + wi] * wc[kh * 3 + kw];
      }
    }
  }
  C1[idx] = acc;
}

// ---------------- BN column-stats (deterministic 2-stage) ----------------
// part layout: [BN_S][2][256]  (stride 512 per stripe)
__global__ void bn_partial(const float* __restrict__ C, int ldc, int M,
                           float* __restrict__ part) {
  int c = blockIdx.x; int s = blockIdx.y; int t = threadIdx.x;
  int rowsPer = (M + BN_S - 1) / BN_S;
  int r0 = s * rowsPer; int r1 = r0 + rowsPer; if (r1 > M) r1 = M;
  float s1 = 0.f, s2 = 0.f;
  for (int r = r0 + t; r < r1; r += 256) {
    float v = C[(size_t)r * ldc + c]; s1 += v; s2 += v * v;
  }
  __shared__ float l1[256], l2[256];
  l1[t] = s1; l2[t] = s2; __syncthreads();
  for (int off = 128; off > 0; off >>= 1) {
    if (t < off) { l1[t] += l1[t + off]; l2[t] += l2[t + off]; }
    __syncthreads();
  }
  if (t == 0) { part[s * 512 + c] = l1[0]; part[s * 512 + 256 + c] = l2[0]; }
}

__global__ void bn_final(const float* __restrict__ part, const float* __restrict__ gamma,
                         const float* __restrict__ beta, float* __restrict__ ss,
                         int C, int M) {
  int c = threadIdx.x;
  if (c >= C) { if (c < 256) { ss[c] = 0.f; ss[256 + c] = 0.f; } return; }
  float s1 = 0.f, s2 = 0.f;
#pragma unroll
  for (int s = 0; s < BN_S; s++) { s1 += part[s * 512 + c]; s2 += part[s * 512 + 256 + c]; }
  float mu = s1 / M;
  float var = s2 / M - mu * mu;
  float sc = gamma[c] * rsqrtf(var + BN_EPS);
  ss[c] = sc; ss[256 + c] = beta[c] - mu * sc;
}

// ---------------- fused BN+ReLU + im2col -> bf16 X[row][tap*Ci+ci] ----------------
__global__ void bnrelu_im2col(const float* __restrict__ Cprev, int ldprev, int Hp, int Wp,
                              const float* __restrict__ ss, u16* __restrict__ X,
                              int Ho, int Wo, int Ci, int Mp) {
  int civ4 = Ci >> 2;
  int idx = blockIdx.x * blockDim.x + threadIdx.x;
  int total = Mp * 9 * civ4;
  if (idx >= total) return;
  int cv = idx % civ4; int t2 = idx / civ4;
  int tap = t2 % 9; int row = t2 / 9;
  int K = 9 * Ci;
  u16* dst = X + (size_t)row * K + tap * Ci + cv * 4;
  int HW = Ho * Wo;
  int Mvalid = 64 * HW;
  ushort4 o4; o4.x = 0; o4.y = 0; o4.z = 0; o4.w = 0;
  if (row < Mvalid) {
    int wo = row % Wo; int t = row / Wo;
    int ho = t % Ho; int n = t / Ho;
    int kh = tap / 3, kw = tap % 3;
    int hi = ho * 2 - 1 + kh, wi = wo * 2 - 1 + kw;
    if (hi >= 0 && hi < Hp && wi >= 0 && wi < Wp) {
      const float* src = Cprev + ((size_t)((n * Hp + hi) * Wp + wi)) * ldprev + cv * 4;
      float4 v = *(const float4*)src;
      int c0 = cv * 4;
      float a;
      a = v.x * ss[c0 + 0] + ss[256 + c0 + 0]; o4.x = f2bf(a > 0.f ? a : 0.f);
      a = v.y * ss[c0 + 1] + ss[256 + c0 + 1]; o4.y = f2bf(a > 0.f ? a : 0.f);
      a = v.z * ss[c0 + 2] + ss[256 + c0 + 2]; o4.z = f2bf(a > 0.f ? a : 0.f);
      a = v.w * ss[c0 + 3] + ss[256 + c0 + 3]; o4.w = f2bf(a > 0.f ? a : 0.f);
    }
  }
  *(ushort4*)dst = o4;
}

// ---------------- conv weight pack: Wp[co][tap*Ci+ci], rows padded to Cop ----------------
__global__ void pack_convw(const float* __restrict__ w, u16* __restrict__ Wp,
                           int Co, int Ci, int Cop) {
  int K = 9 * Ci;
  int idx = blockIdx.x * blockDim.x + threadIdx.x;
  if (idx >= Cop * K) return;
  int k = idx % K; int co = idx / K;
  int tap = k / Ci; int ci = k % Ci;
  float v = (co < Co) ? w[((size_t)co * Ci + ci) * 9 + tap] : 0.f;
  Wp[idx] = f2bf(v);
}

__global__ void pad_bias(const float* __restrict__ b, float* __restrict__ bc, int Co, int Cop) {
  int i = blockIdx.x * blockDim.x + threadIdx.x;
  if (i < Cop) bc[i] = (i < Co) ? b[i] : 0.f;
}

// ---------------- obj pack from C4 (NHWC [1664][256]) with BN+ReLU ----------------
__global__ void obj_from_c4(const float* __restrict__ C4, const float* __restrict__ ss,
                            u16* __restrict__ obj) {
  int idx = blockIdx.x * blockDim.x + threadIdx.x;
  if (idx >= 1664 * 256) return;
  int c = idx & 255; int row = idx >> 8;
  float v = 0.f;
  if (row < 1600) {
    float x = C4[(size_t)row * 256 + c];
    x = x * ss[c] + ss[256 + c];
    v = x > 0.f ? x : 0.f;
  }
  obj[idx] = f2bf(v);
}

// ---------------- MLP weight packs ----------------
__global__ void pack_w1(const float* __restrict__ gw1, u16* __restrict__ W1a, u16* __restrict__ W1b) {
  int idx = blockIdx.x * blockDim.x + threadIdx.x;
  if (idx >= 2048 * 256) return;
  int k = idx & 255, n = idx >> 8;
  float a = 0.f, b = 0.f;
  if (n < 2000) { a = gw1[(size_t)n * 523 + k]; b = gw1[(size_t)n * 523 + 256 + k]; }
  W1a[idx] = f2bf(a); W1b[idx] = f2bf(b);
}

__global__ void pack_wbig(const float* __restrict__ gw, u16* __restrict__ Wp) {
  int idx = blockIdx.x * blockDim.x + threadIdx.x;
  if (idx >= 2048 * 2048) return;
  int k = idx & 2047, n = idx >> 11;
  float v = (n < 2000 && k < 2000) ? gw[(size_t)n * 2000 + k] : 0.f;
  Wp[idx] = f2bf(v);
}

__global__ void pack_bias3(const float* __restrict__ b2, const float* __restrict__ b3,
                           const float* __restrict__ b4, float* __restrict__ bp) {
  int i = blockIdx.x * blockDim.x + threadIdx.x;
  if (i >= 2048) return;
  bp[i]        = (i < 2000) ? b2[i] : 0.f;
  bp[2048 + i] = (i < 2000) ? b3[i] : 0.f;
  bp[4096 + i] = (i < 2000) ? b4[i] : 0.f;
}

// ---------------- Q[b][o] = gb1[o] + qst[b] . gw1[o][512:523] ----------------
__global__ void q_build(const float* __restrict__ qst, const float* __restrict__ gw1,
                        const float* __restrict__ gb1, float* __restrict__ Q) {
  int idx = blockIdx.x * blockDim.x + threadIdx.x;
  if (idx >= 64 * 2048) return;
  int o = idx & 2047, b = idx >> 11;
  float v = 0.f;
  if (o < 2000) {
    v = gb1[o];
    const float* w = gw1 + (size_t)o * 523 + 512;
    const float* q = qst + b * 11;
#pragma unroll
    for (int k = 0; k < 11; k++) v += q[k] * w[k];
  }
  Q[idx] = v;
}

// ---------------- bf16 MFMA GEMM: C[m][n] = sum_k A[m][k]*W[n][k] ----------------
typedef const __attribute__((address_space(1))) u32* gas1;
typedef __attribute__((address_space(3))) u32* las3;
__device__ __forceinline__ void gld16(const void* g, void* l) {
  __builtin_amdgcn_global_load_lds((gas1)g, (las3)l, 16, 0, 0);
}

// EPI 0: fp32 store raw; EPI 1: bf16 store relu(acc+bias); EPI 2: fp32 store acc+bias
template <int EPI>
__global__ __launch_bounds__(256) void gemm_bt(
    const u16* __restrict__ A, int lda,
    const u16* __restrict__ W, int ldb,
    float* __restrict__ Cf, u16* __restrict__ Cb, int ldc,
    const float* __restrict__ bias, int KT, int NTN) {
  __shared__ __align__(16) char lds[32768];  // 2 bufs x (A 8K | W 8K)
  int bid = blockIdx.x;
  int wg;
  if ((gridDim.x & 7) == 0) {
    int cpx = gridDim.x >> 3;
    wg = (bid & 7) * cpx + (bid >> 3);  // XCD-aware swizzle
  } else {
    wg = bid;
  }
  int mt = wg / NTN, nt = wg % NTN;
  int tid = threadIdx.x;
  int wave = tid >> 6, lane = tid & 63;
  int r = lane & 15, g = lane >> 4;
  int wr = wave >> 1, wc = wave & 1;

  const u16* Asrc = A + (size_t)(mt * 128 + wave * 32 + r) * lda + g * 8;
  const u16* Wsrc = W + (size_t)(nt * 128 + wave * 32 + r) * ldb + g * 8;

  f32x4 acc[4][4];
#pragma unroll
  for (int i = 0; i < 4; i++)
#pragma unroll
    for (int j = 0; j < 4; j++) acc[i][j] = (f32x4){0.f, 0.f, 0.f, 0.f};

  {  // stage kt=0 into buf0
    char* Al = lds; char* Wl = lds + 8192;
    gld16(Asrc, Al + wave * 2048);
    gld16(Asrc + (size_t)16 * lda, Al + wave * 2048 + 1024);
    gld16(Wsrc, Wl + wave * 2048);
    gld16(Wsrc + (size_t)16 * ldb, Wl + wave * 2048 + 1024);
  }
  __syncthreads();

  int buf = 0;
  for (int kt = 0; kt < KT; kt++) {
    if (kt + 1 < KT) {
      int k0 = (kt + 1) * 32;
      char* Al = lds + (buf ^ 1) * 16384; char* Wl = Al + 8192;
      gld16(Asrc + k0, Al + wave * 2048);
      gld16(Asrc + k0 + (size_t)16 * lda, Al + wave * 2048 + 1024);
      gld16(Wsrc + k0, Wl + wave * 2048);
      gld16(Wsrc + k0 + (size_t)16 * ldb, Wl + wave * 2048 + 1024);
    }
    char* Al = lds + buf * 16384; char* Wl = Al + 8192;
    bf16x8 a[4], w[4];
#pragma unroll
    for (int i = 0; i < 4; i++) a[i] = *(const bf16x8*)(Al + (wr * 4 + i) * 1024 + lane * 16);
#pragma unroll
    for (int j = 0; j < 4; j++) w[j] = *(const bf16x8*)(Wl + (wc * 4 + j) * 1024 + lane * 16);
#pragma unroll
    for (int i = 0; i < 4; i++)
#pragma unroll
      for (int j = 0; j < 4; j++)
        acc[i][j] = __builtin_amdgcn_mfma_f32_16x16x32_bf16(a[i], w[j], acc[i][j], 0, 0, 0);
    __syncthreads();
    buf ^= 1;
  }

  int rowb = mt * 128 + wr * 64 + (lane >> 4) * 4;
  int colb = nt * 128 + wc * 64 + (lane & 15);
#pragma unroll
  for (int i = 0; i < 4; i++) {
#pragma unroll
    for (int j = 0; j < 4; j++) {
      int col = colb + j * 16;
      float bv = (EPI != 0) ? bias[col] : 0.f;
#pragma unroll
      for (int q = 0; q < 4; q++) {
        int row = rowb + i * 16 + q;
        float v = acc[i][j][q];
        if (EPI == 1) {
          v += bv; v = v > 0.f ? v : 0.f;
          Cb[(size_t)row * ldc + col] = f2bf(v);
        } else if (EPI == 2) {
          Cf[(size_t)row * ldc + col] = v + bv;
        } else {
          Cf[(size_t)row * ldc + col] = v;
        }
      }
    }
  }
}

// ---------------- h1 = relu(A_i + B_j + Q_b), bf16 ----------------
__global__ void h1_build(const float* __restrict__ Afull, const float* __restrict__ Bfull,
                         const float* __restrict__ Q, u16* __restrict__ h1,
                         int c0, int nrows) {
  int row = blockIdx.x;
  int t = threadIdx.x;
  u16* dst = h1 + (size_t)row * 2048;
  if (row >= nrows) {
#pragma unroll
    for (int it = 0; it < 2; it++) {
      int o = it * 1024 + t * 4;
      ushort4 z; z.x = 0; z.y = 0; z.z = 0; z.w = 0;
      *(ushort4*)(dst + o) = z;
    }
    return;
  }
  int b_local = row / 625; int rem = row % 625;
  int i = rem / 25, j = rem % 25;
  int b = c0 + b_local;
  const float* Ap = Afull + (size_t)(b * 25 + i) * 2048;
  const float* Bp = Bfull + (size_t)(b * 25 + j) * 2048;
  const float* Qp = Q + (size_t)b * 2048;
#pragma unroll
  for (int it = 0; it < 2; it++) {
    int o = it * 1024 + t * 4;
    float4 av = *(const float4*)(Ap + o);
    float4 bv = *(const float4*)(Bp + o);
    float4 qv = *(const float4*)(Qp + o);
    ushort4 outv;
    float v;
    v = av.x + bv.x + qv.x; outv.x = f2bf(v > 0.f ? v : 0.f);
    v = av.y + bv.y + qv.y; outv.y = f2bf(v > 0.f ? v : 0.f);
    v = av.z + bv.z + qv.z; outv.z = f2bf(v > 0.f ? v : 0.f);
    v = av.w + bv.w + qv.w; outv.w = f2bf(v > 0.f ? v : 0.f);
    *(ushort4*)(dst + o) = outv;
  }
}

// ---------------- pair-sum reduce: coalesced, deterministic 2-stage ----------------
// grid (CHI, 5); each block: 256 threads x 8 consecutive o's, 125 k-rows.
__global__ void reduce_part(const u16* __restrict__ h4, float* __restrict__ part, int CHI) {
  int bl = blockIdx.x; int s = blockIdx.y; int t = threadIdx.x;
  int k0 = s * 125, k1 = k0 + 125;
  const u16* base = h4 + ((size_t)bl * 625) * 2048 + t * 8;
  float acc0 = 0.f, acc1 = 0.f, acc2 = 0.f, acc3 = 0.f;
  float acc4 = 0.f, acc5 = 0.f, acc6 = 0.f, acc7 = 0.f;
  for (int k = k0; k < k1; k++) {
    uint4 u = *(const uint4*)(base + (size_t)k * 2048);
    acc0 += bf2f((u16)(u.x & 0xffff)); acc1 += bf2f((u16)(u.x >> 16));
    acc2 += bf2f((u16)(u.y & 0xffff)); acc3 += bf2f((u16)(u.y >> 16));
    acc4 += bf2f((u16)(u.z & 0xffff)); acc5 += bf2f((u16)(u.z >> 16));
    acc6 += bf2f((u16)(u.w & 0xffff)); acc7 += bf2f((u16)(u.w >> 16));
  }
  float* dst = part + (((size_t)s * CHI + bl) * 2048) + t * 8;
  dst[0] = acc0; dst[1] = acc1; dst[2] = acc2; dst[3] = acc3;
  dst[4] = acc4; dst[5] = acc5; dst[6] = acc6; dst[7] = acc7;
}

__global__ void reduce_fin(const float* __restrict__ part, float* __restrict__ xg,
                           int c0, int CHI) {
  int idx = blockIdx.x * blockDim.x + threadIdx.x;
  if (idx >= CHI * 2048) return;
  int bl = idx >> 11; int o = idx & 2047;
  float sv = 0.f;
#pragma unroll
  for (int st = 0; st < 5; st++) sv += part[((size_t)st * CHI + bl) * 2048 + o];
  xg[(size_t)(c0 + bl) * 2048 + o] = sv;
}

// ---------------- f MLP: warp per output, fp32 ----------------
__global__ void f_layer(const float* __restrict__ x, int ldx, int Kin,
                        const float* __restrict__ Wf, const float* __restrict__ bf_,
                        float* __restrict__ y, int ldy, int Nout, float scale, int relu) {
  int gwid = (blockIdx.x * blockDim.x + threadIdx.x) >> 6;
  int lane = threadIdx.x & 63;
  if (gwid >= 64 * Nout) return;
  int b = gwid / Nout, o = gwid % Nout;
  const float* xp = x + (size_t)b * ldx;
  const float* wp = Wf + (size_t)o * Kin;
  float s = 0.f;
  for (int k = lane; k < Kin; k += 64) s += xp[k] * wp[k];
  for (int off = 32; off > 0; off >>= 1) s += __shfl_down(s, off);
  if (lane == 0) {
    float v = s * scale + bf_[o];
    if (relu) v = v > 0.f ? v : 0.f;
    y[(size_t)b * ldy + o] = v;
  }
}

__global__ void lsm_kernel(const float* __restrict__ xf4, float* __restrict__ out) {
  int b = blockIdx.x * blockDim.x + threadIdx.x;
  if (b >= 64) return;
  const float* x = xf4 + b * 16;
  float m = x[0];
  for (int i = 1; i < 10; i++) m = fmaxf(m, x[i]);
  float s = 0.f;
  for (int i = 0; i < 10; i++) s += expf(x[i] - m);
  float ls = logf(s);
  for (int i = 0; i < 10; i++) out[b * 10 + i] = x[i] - m - ls;
}

// ---------------- host ----------------
extern "C" void kernel_launch(void* const* d_in, const int* in_sizes, int n_in,
                              void* d_out, int out_size, void* d_ws, size_t ws_size,
                              hipStream_t stream) {
  const float* img = (const float*)d_in[0];
  const float* qst = (const float*)d_in[1];
  const float* w1 = (const float*)d_in[2];  const float* b1 = (const float*)d_in[3];
  const float* w2 = (const float*)d_in[4];  const float* b2 = (const float*)d_in[5];
  const float* w3 = (const float*)d_in[6];  const float* b3 = (const float*)d_in[7];
  const float* w4 = (const float*)d_in[8];  const float* b4 = (const float*)d_in[9];
  const float* g1 = (const float*)d_in[10]; const float* be1 = (const float*)d_in[11];
  const float* g2 = (const float*)d_in[12]; const float* be2 = (const float*)d_in[13];
  const float* g3 = (const float*)d_in[14]; const float* be3 = (const float*)d_in[15];
  const float* g4 = (const float*)d_in[16]; const float* be4 = (const float*)d_in[17];
  const float* gw1 = (const float*)d_in[18]; const float* gb1 = (const float*)d_in[19];
  const float* gw2 = (const float*)d_in[20]; const float* gb2 = (const float*)d_in[21];
  const float* gw3 = (const float*)d_in[22]; const float* gb3 = (const float*)d_in[23];
  const float* gw4 = (const float*)d_in[24]; const float* gb4 = (const float*)d_in[25];
  const float* fw1 = (const float*)d_in[26]; const float* fb1 = (const float*)d_in[27];
  const float* fw2 = (const float*)d_in[28]; const float* fb2 = (const float*)d_in[29];
  const float* fw3 = (const float*)d_in[30]; const float* fb3 = (const float*)d_in[31];
  const float* fw4 = (const float*)d_in[32]; const float* fb4 = (const float*)d_in[33];
  float* out = (float*)d_out;

  char* p = (char*)d_ws;
  auto alloc = [&](size_t bytes) -> char* {
    char* r = p; p += (bytes + 255) & ~(size_t)255; return r;
  };
  // conv path (NHWC)
  float* C1 = (float*)alloc(92416ull * 32 * 4);     // 11.8MB
  u16*   X2 = (u16*)alloc(23168ull * 288 * 2);      // 13.3MB
  float* C2 = (float*)alloc(23168ull * 128 * 4);    // 11.9MB
  u16*   X3 = (u16*)alloc(6400ull * 576 * 2);       // 7.4MB
  float* C3 = (float*)alloc(6400ull * 128 * 4);     // 3.3MB
  u16*   X4 = (u16*)alloc(1664ull * 1152 * 2);      // 3.8MB
  float* C4 = (float*)alloc(1664ull * 256 * 4);     // 1.7MB
  u16*  Wc2 = (u16*)alloc(128ull * 288 * 2);
  u16*  Wc3 = (u16*)alloc(128ull * 576 * 2);
  u16*  Wc4 = (u16*)alloc(256ull * 1152 * 2);
  float* bc2 = (float*)alloc(128 * 4);
  float* bc3 = (float*)alloc(128 * 4);
  float* bc4 = (float*)alloc(256 * 4);
  float* bnp = (float*)alloc(BN_S * 512 * 4);       // bn partials
  float* ss  = (float*)alloc(512 * 4);              // scale/shift
  // MLP path
  u16* obj = (u16*)alloc(1664ull * 256 * 2);
  u16* W1a = (u16*)alloc(2048ull * 256 * 2);
  u16* W1b = (u16*)alloc(2048ull * 256 * 2);
  u16* Wp2 = (u16*)alloc(2048ull * 2048 * 2);
  u16* Wp3 = (u16*)alloc(2048ull * 2048 * 2);
  u16* Wp4 = (u16*)alloc(2048ull * 2048 * 2);
  float* bp = (float*)alloc(3ull * 2048 * 4);
  float* Q = (float*)alloc(64ull * 2048 * 4);
  float* Afull = (float*)alloc(1664ull * 2048 * 4);
  float* Bfull = (float*)alloc(1664ull * 2048 * 4);
  float* xg = (float*)alloc(64ull * 2048 * 4);
  float* rpart = (float*)alloc(5ull * 64 * 2048 * 4);  // reduce partials (max CHI=64)
  float* xf1 = (float*)alloc(64ull * 1024 * 4);
  float* xf2 = (float*)alloc(64ull * 512 * 4);
  float* xf3 = (float*)alloc(64ull * 128 * 4);
  float* xf4 = (float*)alloc(64ull * 16 * 4);

  // pick largest image-chunk whose ping-pong h-buffers fit the workspace
  size_t fixed_end = (size_t)(p - (char*)d_ws);
  int cands[7] = {64, 32, 16, 8, 4, 2, 1};
  int CHI = 1;
  size_t Mp = ((1ull * 625 + 127) / 128) * 128;
  for (int ci = 0; ci < 7; ci++) {
    size_t mp = (((size_t)cands[ci] * 625 + 127) / 128) * 128;
    size_t hb = (mp * 2048 * 2 + 255) & ~(size_t)255;
    if (fixed_end + 2 * hb <= ws_size) { CHI = cands[ci]; Mp = mp; break; }
  }
  u16* h0 = (u16*)alloc(Mp * 2048 * 2);
  u16* h1b = (u16*)alloc(Mp * 2048 * 2);

  // ---- conv weight/bias packs ----
  pack_convw<<<(128 * 288 + 255) / 256, 256, 0, stream>>>(w2, Wc2, 64, 32, 128);
  pack_convw<<<(128 * 576 + 255) / 256, 256, 0, stream>>>(w3, Wc3, 128, 64, 128);
  pack_convw<<<(256 * 1152 + 255) / 256, 256, 0, stream>>>(w4, Wc4, 256, 128, 256);
  pad_bias<<<1, 256, 0, stream>>>(b2, bc2, 64, 128);
  pad_bias<<<1, 256, 0, stream>>>(b3, bc3, 128, 128);
  pad_bias<<<1, 256, 0, stream>>>(b4, bc4, 256, 256);

  // ---- conv stack: direct conv1, then im2col+GEMM for conv2..4 ----
  conv1_nhwc<<<(92416 * 32 + 255) / 256, 256, 0, stream>>>(img, w1, b1, C1);
  bn_partial<<<dim3(32, BN_S), 256, 0, stream>>>(C1, 32, 92416, bnp);
  bn_final<<<1, 256, 0, stream>>>(bnp, g1, be1, ss, 32, 92416);
  bnrelu_im2col<<<(23168 * 9 * 8 + 255) / 256, 256, 0, stream>>>(C1, 32, 38, 38, ss, X2, 19, 19, 32, 23168);
  gemm_bt<2><<<181, 256, 0, stream>>>(X2, 288, Wc2, 288, C2, nullptr, 128, bc2, 9, 1);

  bn_partial<<<dim3(64, BN_S), 256, 0, stream>>>(C2, 128, 23104, bnp);
  bn_final<<<1, 256, 0, stream>>>(bnp, g2, be2, ss, 64, 23104);
  bnrelu_im2col<<<(6400 * 9 * 16 + 255) / 256, 256, 0, stream>>>(C2, 128, 19, 19, ss, X3, 10, 10, 64, 6400);
  gemm_bt<2><<<50, 256, 0, stream>>>(X3, 576, Wc3, 576, C3, nullptr, 128, bc3, 18, 1);

  bn_partial<<<dim3(128, BN_S), 256, 0, stream>>>(C3, 128, 6400, bnp);
  bn_final<<<1, 256, 0, stream>>>(bnp, g3, be3, ss, 128, 6400);
  bnrelu_im2col<<<(1664 * 9 * 32 + 255) / 256, 256, 0, stream>>>(C3, 128, 10, 10, ss, X4, 5, 5, 128, 1664);
  gemm_bt<2><<<26, 256, 0, stream>>>(X4, 1152, Wc4, 1152, C4, nullptr, 256, bc4, 36, 2);

  bn_partial<<<dim3(256, BN_S), 256, 0, stream>>>(C4, 256, 1600, bnp);
  bn_final<<<1, 256, 0, stream>>>(bnp, g4, be4, ss, 256, 1600);
  obj_from_c4<<<(1664 * 256 + 255) / 256, 256, 0, stream>>>(C4, ss, obj);

  // ---- MLP packs ----
  pack_w1<<<2048, 256, 0, stream>>>(gw1, W1a, W1b);
  pack_wbig<<<16384, 256, 0, stream>>>(gw2, Wp2);
  pack_wbig<<<16384, 256, 0, stream>>>(gw3, Wp3);
  pack_wbig<<<16384, 256, 0, stream>>>(gw4, Wp4);
  pack_bias3<<<8, 256, 0, stream>>>(gb2, gb3, gb4, bp);
  q_build<<<512, 256, 0, stream>>>(qst, gw1, gb1, Q);

  // ---- layer-1 decomposition GEMMs: A = obj @ W1a^T, B = obj @ W1b^T ----
  gemm_bt<0><<<13 * 16, 256, 0, stream>>>(obj, 256, W1a, 256, Afull, nullptr, 2048, nullptr, 8, 16);
  gemm_bt<0><<<13 * 16, 256, 0, stream>>>(obj, 256, W1b, 256, Bfull, nullptr, 2048, nullptr, 8, 16);

  // ---- chunked g-MLP ----
  int NC = 64 / CHI;
  int mtiles = (int)(Mp / 128);
  for (int c = 0; c < NC; c++) {
    int c0 = c * CHI;
    int nrows = CHI * 625;
    h1_build<<<(unsigned)Mp, 256, 0, stream>>>(Afull, Bfull, Q, h0, c0, nrows);
    gemm_bt<1><<<mtiles * 16, 256, 0, stream>>>(h0, 2048, Wp2, 2048, nullptr, h1b, 2048, bp, 64, 16);
    gemm_bt<1><<<mtiles * 16, 256, 0, stream>>>(h1b, 2048, Wp3, 2048, nullptr, h0, 2048, bp + 2048, 64, 16);
    gemm_bt<1><<<mtiles * 16, 256, 0, stream>>>(h0, 2048, Wp4, 2048, nullptr, h1b, 2048, bp + 4096, 64, 16);
    reduce_part<<<dim3(CHI, 5), 256, 0, stream>>>(h1b, rpart, CHI);
    reduce_fin<<<(CHI * 2048 + 255) / 256, 256, 0, stream>>>(rpart, xg, c0, CHI);
  }

  // ---- f MLP ----
  {
    int nthreads;
    nthreads = 64 * 1000 * 64;
    f_layer<<<(nthreads + 255) / 256, 256, 0, stream>>>(xg, 2048, 2000, fw1, fb1, xf1, 1024, 1000, 1.f / 625.f, 1);
    nthreads = 64 * 500 * 64;
    f_layer<<<(nthreads + 255) / 256, 256, 0, stream>>>(xf1, 1024, 1000, fw2, fb2, xf2, 512, 500, 1.f, 1);
    nthreads = 64 * 100 * 64;
    f_layer<<<(nthreads + 255) / 256, 256, 0, stream>>>(xf2, 512, 500, fw3, fb3, xf3, 128, 100, 1.f, 1);
    nthreads = 64 * 10 * 64;
    f_layer<<<(nthreads + 255) / 256, 256, 0, stream>>>(xf3, 128, 100, fw4, fb4, xf4, 16, 10, 1.f, 0);
  }
  lsm_kernel<<<1, 64, 0, stream>>>(xf4, out);
}

// Round 3
// 1861.535 us; speedup vs baseline: 1.8687x; 1.2847x over previous
//
#include <hip/hip_runtime.h>

typedef unsigned short u16;
typedef unsigned int u32;
typedef __attribute__((ext_vector_type(8))) short bf16x8;
typedef __attribute__((ext_vector_type(4))) float f32x4;

#define BN_EPS 1e-5f
#define BN_S 16

__device__ __forceinline__ float bf2f(u16 u) {
  union { unsigned u; float f; } x; x.u = ((unsigned)u) << 16; return x.f;
}
__device__ __forceinline__ u16 f2bf(float f) {
  union { float f; unsigned u; } x; x.f = f;
  unsigned r = x.u + 0x7FFFu + ((x.u >> 16) & 1u);
  return (u16)(r >> 16);
}

// ---------------- conv1: direct, NHWC output [64*38*38][32] fp32 ----------------
__global__ void conv1_nhwc(const float* __restrict__ img, const float* __restrict__ w,
                           const float* __restrict__ b, float* __restrict__ C1) {
  int idx = blockIdx.x * blockDim.x + threadIdx.x;
  if (idx >= 92416 * 32) return;
  int co = idx & 31; int row = idx >> 5;
  int wo = row % 38; int t = row / 38;
  int ho = t % 38; int n = t / 38;
  int hi0 = ho * 2 - 1, wi0 = wo * 2 - 1;
  float acc = b[co];
  const float* wp = w + co * 27;
#pragma unroll
  for (int ci = 0; ci < 3; ci++) {
    const float* ip = img + ((size_t)(n * 3 + ci) * 75) * 75;
    const float* wc = wp + ci * 9;
#pragma unroll
    for (int kh = 0; kh < 3; kh++) {
      int hi = hi0 + kh;
      if (hi < 0 || hi >= 75) continue;
#pragma unroll
      for (int kw = 0; kw < 3; kw++) {
        int wi = wi0 + kw;
        if (wi < 0 || wi >= 75) continue;
        acc += ip[hi * 75 + wi] * wc[kh * 3 + kw];
      }
    }
  }
  C1[idx] = acc;
}

// ---------------- BN column-stats (deterministic 2-stage) ----------------
__global__ void bn_partial(const float* __restrict__ C, int ldc, int M,
                           float* __restrict__ part) {
  int c = blockIdx.x; int s = blockIdx.y; int t = threadIdx.x;
  int rowsPer = (M + BN_S - 1) / BN_S;
  int r0 = s * rowsPer; int r1 = r0 + rowsPer; if (r1 > M) r1 = M;
  float s1 = 0.f, s2 = 0.f;
  for (int r = r0 + t; r < r1; r += 256) {
    float v = C[(size_t)r * ldc + c]; s1 += v; s2 += v * v;
  }
  __shared__ float l1[256], l2[256];
  l1[t] = s1; l2[t] = s2; __syncthreads();
  for (int off = 128; off > 0; off >>= 1) {
    if (t < off) { l1[t] += l1[t + off]; l2[t] += l2[t + off]; }
    __syncthreads();
  }
  if (t == 0) { part[s * 512 + c] = l1[0]; part[s * 512 + 256 + c] = l2[0]; }
}

__global__ void bn_final(const float* __restrict__ part, const float* __restrict__ gamma,
                         const float* __restrict__ beta, float* __restrict__ ss,
                         int C, int M) {
  int c = threadIdx.x;
  if (c >= C) { if (c < 256) { ss[c] = 0.f; ss[256 + c] = 0.f; } return; }
  float s1 = 0.f, s2 = 0.f;
#pragma unroll
  for (int s = 0; s < BN_S; s++) { s1 += part[s * 512 + c]; s2 += part[s * 512 + 256 + c]; }
  float mu = s1 / M;
  float var = s2 / M - mu * mu;
  float sc = gamma[c] * rsqrtf(var + BN_EPS);
  ss[c] = sc; ss[256 + c] = beta[c] - mu * sc;
}

// ---------------- fused BN+ReLU + im2col -> bf16 X[row][tap*Ci+ci] ----------------
__global__ void bnrelu_im2col(const float* __restrict__ Cprev, int ldprev, int Hp, int Wp,
                              const float* __restrict__ ss, u16* __restrict__ X,
                              int Ho, int Wo, int Ci, int Mp) {
  int civ4 = Ci >> 2;
  int idx = blockIdx.x * blockDim.x + threadIdx.x;
  int total = Mp * 9 * civ4;
  if (idx >= total) return;
  int cv = idx % civ4; int t2 = idx / civ4;
  int tap = t2 % 9; int row = t2 / 9;
  int K = 9 * Ci;
  u16* dst = X + (size_t)row * K + tap * Ci + cv * 4;
  int HW = Ho * Wo;
  int Mvalid = 64 * HW;
  ushort4 o4; o4.x = 0; o4.y = 0; o4.z = 0; o4.w = 0;
  if (row < Mvalid) {
    int wo = row % Wo; int t = row / Wo;
    int ho = t % Ho; int n = t / Ho;
    int kh = tap / 3, kw = tap % 3;
    int hi = ho * 2 - 1 + kh, wi = wo * 2 - 1 + kw;
    if (hi >= 0 && hi < Hp && wi >= 0 && wi < Wp) {
      const float* src = Cprev + ((size_t)((n * Hp + hi) * Wp + wi)) * ldprev + cv * 4;
      float4 v = *(const float4*)src;
      int c0 = cv * 4;
      float a;
      a = v.x * ss[c0 + 0] + ss[256 + c0 + 0]; o4.x = f2bf(a > 0.f ? a : 0.f);
      a = v.y * ss[c0 + 1] + ss[256 + c0 + 1]; o4.y = f2bf(a > 0.f ? a : 0.f);
      a = v.z * ss[c0 + 2] + ss[256 + c0 + 2]; o4.z = f2bf(a > 0.f ? a : 0.f);
      a = v.w * ss[c0 + 3] + ss[256 + c0 + 3]; o4.w = f2bf(a > 0.f ? a : 0.f);
    }
  }
  *(ushort4*)dst = o4;
}

// ---------------- conv weight pack ----------------
__global__ void pack_convw(const float* __restrict__ w, u16* __restrict__ Wp,
                           int Co, int Ci, int Cop) {
  int K = 9 * Ci;
  int idx = blockIdx.x * blockDim.x + threadIdx.x;
  if (idx >= Cop * K) return;
  int k = idx % K; int co = idx / K;
  int tap = k / Ci; int ci = k % Ci;
  float v = (co < Co) ? w[((size_t)co * Ci + ci) * 9 + tap] : 0.f;
  Wp[idx] = f2bf(v);
}

__global__ void pad_bias(const float* __restrict__ b, float* __restrict__ bc, int Co, int Cop) {
  int i = blockIdx.x * blockDim.x + threadIdx.x;
  if (i < Cop) bc[i] = (i < Co) ? b[i] : 0.f;
}

// ---------------- obj pack from C4 with BN+ReLU ----------------
__global__ void obj_from_c4(const float* __restrict__ C4, const float* __restrict__ ss,
                            u16* __restrict__ obj) {
  int idx = blockIdx.x * blockDim.x + threadIdx.x;
  if (idx >= 1664 * 256) return;
  int c = idx & 255; int row = idx >> 8;
  float v = 0.f;
  if (row < 1600) {
    float x = C4[(size_t)row * 256 + c];
    x = x * ss[c] + ss[256 + c];
    v = x > 0.f ? x : 0.f;
  }
  obj[idx] = f2bf(v);
}

// ---------------- MLP weight packs ----------------
__global__ void pack_w1(const float* __restrict__ gw1, u16* __restrict__ W1a, u16* __restrict__ W1b) {
  int idx = blockIdx.x * blockDim.x + threadIdx.x;
  if (idx >= 2048 * 256) return;
  int k = idx & 255, n = idx >> 8;
  float a = 0.f, b = 0.f;
  if (n < 2000) { a = gw1[(size_t)n * 523 + k]; b = gw1[(size_t)n * 523 + 256 + k]; }
  W1a[idx] = f2bf(a); W1b[idx] = f2bf(b);
}

__global__ void pack_wbig(const float* __restrict__ gw, u16* __restrict__ Wp) {
  int idx = blockIdx.x * blockDim.x + threadIdx.x;
  if (idx >= 2048 * 2048) return;
  int k = idx & 2047, n = idx >> 11;
  float v = (n < 2000 && k < 2000) ? gw[(size_t)n * 2000 + k] : 0.f;
  Wp[idx] = f2bf(v);
}

__global__ void pack_bias3(const float* __restrict__ b2, const float* __restrict__ b3,
                           const float* __restrict__ b4, float* __restrict__ bp) {
  int i = blockIdx.x * blockDim.x + threadIdx.x;
  if (i >= 2048) return;
  bp[i]        = (i < 2000) ? b2[i] : 0.f;
  bp[2048 + i] = (i < 2000) ? b3[i] : 0.f;
  bp[4096 + i] = (i < 2000) ? b4[i] : 0.f;
}

// ---------------- Q[b][o] = gb1[o] + qst[b] . gw1[o][512:523] ----------------
__global__ void q_build(const float* __restrict__ qst, const float* __restrict__ gw1,
                        const float* __restrict__ gb1, float* __restrict__ Q) {
  int idx = blockIdx.x * blockDim.x + threadIdx.x;
  if (idx >= 64 * 2048) return;
  int o = idx & 2047, b = idx >> 11;
  float v = 0.f;
  if (o < 2000) {
    v = gb1[o];
    const float* w = gw1 + (size_t)o * 523 + 512;
    const float* q = qst + b * 11;
#pragma unroll
    for (int k = 0; k < 11; k++) v += q[k] * w[k];
  }
  Q[idx] = v;
}

// ---------------- global->LDS async ----------------
typedef const __attribute__((address_space(1))) u32* gas1;
typedef __attribute__((address_space(3))) u32* las3;
__device__ __forceinline__ void gld16(const void* g, void* l) {
  __builtin_amdgcn_global_load_lds((gas1)g, (las3)l, 16, 0, 0);
}

// ---------------- 128^2 bf16 MFMA GEMM (small/medium shapes) ----------------
// EPI 0: fp32 store raw; EPI 2: fp32 store acc+bias
template <int EPI>
__global__ __launch_bounds__(256) void gemm_bt(
    const u16* __restrict__ A, int lda,
    const u16* __restrict__ W, int ldb,
    float* __restrict__ Cf, u16* __restrict__ Cb, int ldc,
    const float* __restrict__ bias, int KT, int NTN) {
  __shared__ __align__(16) char lds[32768];
  int bid = blockIdx.x;
  int wg;
  if ((gridDim.x & 7) == 0) {
    int cpx = gridDim.x >> 3;
    wg = (bid & 7) * cpx + (bid >> 3);
  } else {
    wg = bid;
  }
  int mt = wg / NTN, nt = wg % NTN;
  int tid = threadIdx.x;
  int wave = tid >> 6, lane = tid & 63;
  int r = lane & 15, g = lane >> 4;
  int wr = wave >> 1, wc = wave & 1;

  const u16* Asrc = A + (size_t)(mt * 128 + wave * 32 + r) * lda + g * 8;
  const u16* Wsrc = W + (size_t)(nt * 128 + wave * 32 + r) * ldb + g * 8;

  f32x4 acc[4][4];
#pragma unroll
  for (int i = 0; i < 4; i++)
#pragma unroll
    for (int j = 0; j < 4; j++) acc[i][j] = (f32x4){0.f, 0.f, 0.f, 0.f};

  {
    char* Al = lds; char* Wl = lds + 8192;
    gld16(Asrc, Al + wave * 2048);
    gld16(Asrc + (size_t)16 * lda, Al + wave * 2048 + 1024);
    gld16(Wsrc, Wl + wave * 2048);
    gld16(Wsrc + (size_t)16 * ldb, Wl + wave * 2048 + 1024);
  }
  __syncthreads();

  int buf = 0;
  for (int kt = 0; kt < KT; kt++) {
    if (kt + 1 < KT) {
      int k0 = (kt + 1) * 32;
      char* Al = lds + (buf ^ 1) * 16384; char* Wl = Al + 8192;
      gld16(Asrc + k0, Al + wave * 2048);
      gld16(Asrc + k0 + (size_t)16 * lda, Al + wave * 2048 + 1024);
      gld16(Wsrc + k0, Wl + wave * 2048);
      gld16(Wsrc + k0 + (size_t)16 * ldb, Wl + wave * 2048 + 1024);
    }
    char* Al = lds + buf * 16384; char* Wl = Al + 8192;
    bf16x8 a[4], w[4];
#pragma unroll
    for (int i = 0; i < 4; i++) a[i] = *(const bf16x8*)(Al + (wr * 4 + i) * 1024 + lane * 16);
#pragma unroll
    for (int j = 0; j < 4; j++) w[j] = *(const bf16x8*)(Wl + (wc * 4 + j) * 1024 + lane * 16);
#pragma unroll
    for (int i = 0; i < 4; i++)
#pragma unroll
      for (int j = 0; j < 4; j++)
        acc[i][j] = __builtin_amdgcn_mfma_f32_16x16x32_bf16(a[i], w[j], acc[i][j], 0, 0, 0);
    __syncthreads();
    buf ^= 1;
  }

  int rowb = mt * 128 + wr * 64 + (lane >> 4) * 4;
  int colb = nt * 128 + wc * 64 + (lane & 15);
#pragma unroll
  for (int i = 0; i < 4; i++) {
#pragma unroll
    for (int j = 0; j < 4; j++) {
      int col = colb + j * 16;
      float bv = (EPI != 0) ? bias[col] : 0.f;
#pragma unroll
      for (int q = 0; q < 4; q++) {
        int row = rowb + i * 16 + q;
        float v = acc[i][j][q];
        if (EPI == 2) {
          Cf[(size_t)row * ldc + col] = v + bv;
        } else {
          Cf[(size_t)row * ldc + col] = v;
        }
      }
    }
  }
}

// ---------------- 256^2 counted-vmcnt bf16 GEMM (big g-MLP layers) ----------------
// C[m][n] = relu(sum_k A[m][k]*W[n][k] + bias[n]) -> bf16. lda=ldb=ldc=2048.
// 8 waves (2Mx4N), BK=64, 128KB LDS dbuf, global_load_lds staging,
// counted vmcnt(8) (never 0 in main loop), raw s_barrier, setprio around MFMA.
__global__ __launch_bounds__(512, 2) void gemm256(
    const u16* __restrict__ A, const u16* __restrict__ W,
    u16* __restrict__ Cb, const float* __restrict__ bias, int NT) {
  __shared__ __align__(16) char lds[131072];
  int bid = blockIdx.x;
  int cpx = gridDim.x >> 3;                 // grid = mtiles*8, always %8==0
  int wg = (bid & 7) * cpx + (bid >> 3);
  int mt = wg >> 3, nt = wg & 7;
  int tid = threadIdx.x;
  int wave = tid >> 6, lane = tid & 63;
  int r = lane & 15, g = lane >> 4;
  int wr = wave >> 2, wc = wave & 3;
  const int lda = 2048;

  // per-thread staging source pointers (advance 64 elems = 128B per K-tile)
  const u16* gA[4];
  const u16* gB[4];
#pragma unroll
  for (int i = 0; i < 4; i++) {
    int sub = i * 8 + wave;
    int rb = sub >> 1, ks = sub & 1;
    gA[i] = A + (size_t)(mt * 256 + rb * 16 + r) * lda + ks * 32 + g * 8;
    gB[i] = W + (size_t)(nt * 256 + rb * 16 + r) * lda + ks * 32 + g * 8;
  }

  f32x4 acc[8][4];
#pragma unroll
  for (int i = 0; i < 8; i++)
#pragma unroll
    for (int j = 0; j < 4; j++) acc[i][j] = (f32x4){0.f, 0.f, 0.f, 0.f};

  // prologue: stage tile 0 into buf 0
  {
    char* dstA = lds;
    char* dstB = lds + 32768;
#pragma unroll
    for (int i = 0; i < 4; i++) {
      int sub = i * 8 + wave;
      gld16(gA[i], dstA + sub * 1024);
      gld16(gB[i], dstB + sub * 1024);
      gA[i] += 64; gB[i] += 64;
    }
  }

  int cur = 0;
  for (int t = 0; t < NT; t++) {
    if (t + 1 < NT) {
      char* dstA = lds + (cur ^ 1) * 65536;
      char* dstB = dstA + 32768;
#pragma unroll
      for (int i = 0; i < 4; i++) {
        int sub = i * 8 + wave;
        gld16(gA[i], dstA + sub * 1024);
        gld16(gB[i], dstB + sub * 1024);
        gA[i] += 64; gB[i] += 64;
      }
      asm volatile("s_waitcnt vmcnt(8)" ::: "memory");  // tile t's loads done; t+1's stay in flight
    } else {
      asm volatile("s_waitcnt vmcnt(0)" ::: "memory");  // drain once at last tile
    }
    __builtin_amdgcn_s_barrier();                       // all waves' tile-t data in LDS

    const char* Al = lds + cur * 65536;
    const char* Bl = Al + 32768;
#pragma unroll
    for (int ks = 0; ks < 2; ks++) {
      bf16x8 a[8], b[4];
#pragma unroll
      for (int i = 0; i < 8; i++)
        a[i] = *(const bf16x8*)(Al + (((wr * 8 + i) << 1) + ks) * 1024 + lane * 16);
#pragma unroll
      for (int j = 0; j < 4; j++)
        b[j] = *(const bf16x8*)(Bl + (((wc * 4 + j) << 1) + ks) * 1024 + lane * 16);
      __builtin_amdgcn_s_setprio(1);
#pragma unroll
      for (int i = 0; i < 8; i++)
#pragma unroll
        for (int j = 0; j < 4; j++)
          acc[i][j] = __builtin_amdgcn_mfma_f32_16x16x32_bf16(a[i], b[j], acc[i][j], 0, 0, 0);
      __builtin_amdgcn_s_setprio(0);
    }
    __builtin_amdgcn_s_barrier();  // all waves done reading buf[cur] -> safe to restage next iter
    cur ^= 1;
  }

  // epilogue: frag D layout col=lane&15, row=(lane>>4)*4+q
  int rowb = mt * 256 + wr * 128 + g * 4;
  int colb = nt * 256 + wc * 64 + r;
#pragma unroll
  for (int i = 0; i < 8; i++) {
#pragma unroll
    for (int j = 0; j < 4; j++) {
      int col = colb + j * 16;
      float bv = bias[col];
#pragma unroll
      for (int q = 0; q < 4; q++) {
        int row = rowb + i * 16 + q;
        float v = acc[i][j][q] + bv;
        v = v > 0.f ? v : 0.f;
        Cb[(size_t)row * 2048 + col] = f2bf(v);
      }
    }
  }
}

// ---------------- h1 = relu(A_i + B_j + Q_b), bf16 ----------------
__global__ void h1_build(const float* __restrict__ Afull, const float* __restrict__ Bfull,
                         const float* __restrict__ Q, u16* __restrict__ h1,
                         int c0, int nrows) {
  int row = blockIdx.x;
  int t = threadIdx.x;
  u16* dst = h1 + (size_t)row * 2048;
  if (row >= nrows) {
#pragma unroll
    for (int it = 0; it < 2; it++) {
      int o = it * 1024 + t * 4;
      ushort4 z; z.x = 0; z.y = 0; z.z = 0; z.w = 0;
      *(ushort4*)(dst + o) = z;
    }
    return;
  }
  int b_local = row / 625; int rem = row % 625;
  int i = rem / 25, j = rem % 25;
  int b = c0 + b_local;
  const float* Ap = Afull + (size_t)(b * 25 + i) * 2048;
  const float* Bp = Bfull + (size_t)(b * 25 + j) * 2048;
  const float* Qp = Q + (size_t)b * 2048;
#pragma unroll
  for (int it = 0; it < 2; it++) {
    int o = it * 1024 + t * 4;
    float4 av = *(const float4*)(Ap + o);
    float4 bv = *(const float4*)(Bp + o);
    float4 qv = *(const float4*)(Qp + o);
    ushort4 outv;
    float v;
    v = av.x + bv.x + qv.x; outv.x = f2bf(v > 0.f ? v : 0.f);
    v = av.y + bv.y + qv.y; outv.y = f2bf(v > 0.f ? v : 0.f);
    v = av.z + bv.z + qv.z; outv.z = f2bf(v > 0.f ? v : 0.f);
    v = av.w + bv.w + qv.w; outv.w = f2bf(v > 0.f ? v : 0.f);
    *(ushort4*)(dst + o) = outv;
  }
}

// ---------------- pair-sum reduce, deterministic 2-stage ----------------
__global__ void reduce_part(const u16* __restrict__ h4, float* __restrict__ part, int CHI) {
  int bl = blockIdx.x; int s = blockIdx.y; int t = threadIdx.x;
  int k0 = s * 125, k1 = k0 + 125;
  const u16* base = h4 + ((size_t)bl * 625) * 2048 + t * 8;
  float acc0 = 0.f, acc1 = 0.f, acc2 = 0.f, acc3 = 0.f;
  float acc4 = 0.f, acc5 = 0.f, acc6 = 0.f, acc7 = 0.f;
  for (int k = k0; k < k1; k++) {
    uint4 u = *(const uint4*)(base + (size_t)k * 2048);
    acc0 += bf2f((u16)(u.x & 0xffff)); acc1 += bf2f((u16)(u.x >> 16));
    acc2 += bf2f((u16)(u.y & 0xffff)); acc3 += bf2f((u16)(u.y >> 16));
    acc4 += bf2f((u16)(u.z & 0xffff)); acc5 += bf2f((u16)(u.z >> 16));
    acc6 += bf2f((u16)(u.w & 0xffff)); acc7 += bf2f((u16)(u.w >> 16));
  }
  float* dst = part + (((size_t)s * CHI + bl) * 2048) + t * 8;
  dst[0] = acc0; dst[1] = acc1; dst[2] = acc2; dst[3] = acc3;
  dst[4] = acc4; dst[5] = acc5; dst[6] = acc6; dst[7] = acc7;
}

__global__ void reduce_fin(const float* __restrict__ part, float* __restrict__ xg,
                           int c0, int CHI) {
  int idx = blockIdx.x * blockDim.x + threadIdx.x;
  if (idx >= CHI * 2048) return;
  int bl = idx >> 11; int o = idx & 2047;
  float sv = 0.f;
#pragma unroll
  for (int st = 0; st < 5; st++) sv += part[((size_t)st * CHI + bl) * 2048 + o];
  xg[(size_t)(c0 + bl) * 2048 + o] = sv;
}

// ---------------- f MLP: warp per output, fp32 ----------------
__global__ void f_layer(const float* __restrict__ x, int ldx, int Kin,
                        const float* __restrict__ Wf, const float* __restrict__ bf_,
                        float* __restrict__ y, int ldy, int Nout, float scale, int relu) {
  int gwid = (blockIdx.x * blockDim.x + threadIdx.x) >> 6;
  int lane = threadIdx.x & 63;
  if (gwid >= 64 * Nout) return;
  int b = gwid / Nout, o = gwid % Nout;
  const float* xp = x + (size_t)b * ldx;
  const float* wp = Wf + (size_t)o * Kin;
  float s = 0.f;
  for (int k = lane; k < Kin; k += 64) s += xp[k] * wp[k];
  for (int off = 32; off > 0; off >>= 1) s += __shfl_down(s, off);
  if (lane == 0) {
    float v = s * scale + bf_[o];
    if (relu) v = v > 0.f ? v : 0.f;
    y[(size_t)b * ldy + o] = v;
  }
}

__global__ void lsm_kernel(const float* __restrict__ xf4, float* __restrict__ out) {
  int b = blockIdx.x * blockDim.x + threadIdx.x;
  if (b >= 64) return;
  const float* x = xf4 + b * 16;
  float m = x[0];
  for (int i = 1; i < 10; i++) m = fmaxf(m, x[i]);
  float s = 0.f;
  for (int i = 0; i < 10; i++) s += expf(x[i] - m);
  float ls = logf(s);
  for (int i = 0; i < 10; i++) out[b * 10 + i] = x[i] - m - ls;
}

// ---------------- host ----------------
extern "C" void kernel_launch(void* const* d_in, const int* in_sizes, int n_in,
                              void* d_out, int out_size, void* d_ws, size_t ws_size,
                              hipStream_t stream) {
  const float* img = (const float*)d_in[0];
  const float* qst = (const float*)d_in[1];
  const float* w1 = (const float*)d_in[2];  const float* b1 = (const float*)d_in[3];
  const float* w2 = (const float*)d_in[4];  const float* b2 = (const float*)d_in[5];
  const float* w3 = (const float*)d_in[6];  const float* b3 = (const float*)d_in[7];
  const float* w4 = (const float*)d_in[8];  const float* b4 = (const float*)d_in[9];
  const float* g1 = (const float*)d_in[10]; const float* be1 = (const float*)d_in[11];
  const float* g2 = (const float*)d_in[12]; const float* be2 = (const float*)d_in[13];
  const float* g3 = (const float*)d_in[14]; const float* be3 = (const float*)d_in[15];
  const float* g4 = (const float*)d_in[16]; const float* be4 = (const float*)d_in[17];
  const float* gw1 = (const float*)d_in[18]; const float* gb1 = (const float*)d_in[19];
  const float* gw2 = (const float*)d_in[20]; const float* gb2 = (const float*)d_in[21];
  const float* gw3 = (const float*)d_in[22]; const float* gb3 = (const float*)d_in[23];
  const float* gw4 = (const float*)d_in[24]; const float* gb4 = (const float*)d_in[25];
  const float* fw1 = (const float*)d_in[26]; const float* fb1 = (const float*)d_in[27];
  const float* fw2 = (const float*)d_in[28]; const float* fb2 = (const float*)d_in[29];
  const float* fw3 = (const float*)d_in[30]; const float* fb3 = (const float*)d_in[31];
  const float* fw4 = (const float*)d_in[32]; const float* fb4 = (const float*)d_in[33];
  float* out = (float*)d_out;

  // ---- persistent region ----
  char* P = (char*)d_ws;
  auto alloc = [&](size_t bytes) -> char* {
    char* r = P; P += (bytes + 255) & ~(size_t)255; return r;
  };
  u16* Wp2 = (u16*)alloc(2048ull * 2048 * 2);
  u16* Wp3 = (u16*)alloc(2048ull * 2048 * 2);
  u16* Wp4 = (u16*)alloc(2048ull * 2048 * 2);
  float* Afull = (float*)alloc(1664ull * 2048 * 4);
  float* Bfull = (float*)alloc(1664ull * 2048 * 4);
  float* Q = (float*)alloc(64ull * 2048 * 4);
  float* bp = (float*)alloc(3ull * 2048 * 4);
  u16* W1a = (u16*)alloc(2048ull * 256 * 2);
  u16* W1b = (u16*)alloc(2048ull * 256 * 2);
  u16* obj = (u16*)alloc(1664ull * 256 * 2);
  float* xg = (float*)alloc(64ull * 2048 * 4);
  float* xf1 = (float*)alloc(64ull * 1024 * 4);
  float* xf2 = (float*)alloc(64ull * 512 * 4);
  float* xf3 = (float*)alloc(64ull * 128 * 4);
  float* xf4 = (float*)alloc(64ull * 16 * 4);

  // ---- scratch region (conv buffers and h buffers alias each other) ----
  char* scratch = P;
  size_t scratch_avail = ws_size - (size_t)(scratch - (char*)d_ws);
  auto salloc = [&](char*& sp, size_t bytes) -> char* {
    char* r = sp; sp += (bytes + 255) & ~(size_t)255; return r;
  };
  // conv-phase buffers (dead after obj is built)
  char* sp = scratch;
  float* C1 = (float*)salloc(sp, 92416ull * 32 * 4);
  u16*   X2 = (u16*)salloc(sp, 23168ull * 288 * 2);
  float* C2 = (float*)salloc(sp, 23168ull * 128 * 4);
  u16*   X3 = (u16*)salloc(sp, 6400ull * 576 * 2);
  float* C3 = (float*)salloc(sp, 6400ull * 128 * 4);
  u16*   X4 = (u16*)salloc(sp, 1664ull * 1152 * 2);
  float* C4 = (float*)salloc(sp, 1664ull * 256 * 4);
  u16*  Wc2 = (u16*)salloc(sp, 128ull * 288 * 2);
  u16*  Wc3 = (u16*)salloc(sp, 128ull * 576 * 2);
  u16*  Wc4 = (u16*)salloc(sp, 256ull * 1152 * 2);
  float* bc2 = (float*)salloc(sp, 128 * 4);
  float* bc3 = (float*)salloc(sp, 128 * 4);
  float* bc4 = (float*)salloc(sp, 256 * 4);
  float* bnp = (float*)salloc(sp, BN_S * 512 * 4);
  float* ss  = (float*)salloc(sp, 512 * 4);

  // h-phase buffers: pick largest CHI whose buffers fit scratch
  int cands[7] = {64, 32, 16, 8, 4, 2, 1};
  int CHI = 1;
  size_t Mp = 768;
  for (int ci = 0; ci < 7; ci++) {
    size_t mp = (((size_t)cands[ci] * 625 + 255) / 256) * 256;
    size_t hb = (mp * 2048 * 2 + 255) & ~(size_t)255;
    size_t rp = ((size_t)5 * cands[ci] * 2048 * 4 + 255) & ~(size_t)255;
    if (2 * hb + rp <= scratch_avail) {
      CHI = cands[ci]; Mp = mp; break;
    }
  }
  char* hp = scratch;
  u16* h0  = (u16*)salloc(hp, Mp * 2048 * 2);
  u16* h1b = (u16*)salloc(hp, Mp * 2048 * 2);
  float* rpart = (float*)salloc(hp, (size_t)5 * CHI * 2048 * 4);

  // ---- conv weight/bias packs ----
  pack_convw<<<(128 * 288 + 255) / 256, 256, 0, stream>>>(w2, Wc2, 64, 32, 128);
  pack_convw<<<(128 * 576 + 255) / 256, 256, 0, stream>>>(w3, Wc3, 128, 64, 128);
  pack_convw<<<(256 * 1152 + 255) / 256, 256, 0, stream>>>(w4, Wc4, 256, 128, 256);
  pad_bias<<<1, 256, 0, stream>>>(b2, bc2, 64, 128);
  pad_bias<<<1, 256, 0, stream>>>(b3, bc3, 128, 128);
  pad_bias<<<1, 256, 0, stream>>>(b4, bc4, 256, 256);

  // ---- conv stack ----
  conv1_nhwc<<<(92416 * 32 + 255) / 256, 256, 0, stream>>>(img, w1, b1, C1);
  bn_partial<<<dim3(32, BN_S), 256, 0, stream>>>(C1, 32, 92416, bnp);
  bn_final<<<1, 256, 0, stream>>>(bnp, g1, be1, ss, 32, 92416);
  bnrelu_im2col<<<(23168 * 9 * 8 + 255) / 256, 256, 0, stream>>>(C1, 32, 38, 38, ss, X2, 19, 19, 32, 23168);
  gemm_bt<2><<<181, 256, 0, stream>>>(X2, 288, Wc2, 288, C2, nullptr, 128, bc2, 9, 1);

  bn_partial<<<dim3(64, BN_S), 256, 0, stream>>>(C2, 128, 23104, bnp);
  bn_final<<<1, 256, 0, stream>>>(bnp, g2, be2, ss, 64, 23104);
  bnrelu_im2col<<<(6400 * 9 * 16 + 255) / 256, 256, 0, stream>>>(C2, 128, 19, 19, ss, X3, 10, 10, 64, 6400);
  gemm_bt<2><<<50, 256, 0, stream>>>(X3, 576, Wc3, 576, C3, nullptr, 128, bc3, 18, 1);

  bn_partial<<<dim3(128, BN_S), 256, 0, stream>>>(C3, 128, 6400, bnp);
  bn_final<<<1, 256, 0, stream>>>(bnp, g3, be3, ss, 128, 6400);
  bnrelu_im2col<<<(1664 * 9 * 32 + 255) / 256, 256, 0, stream>>>(C3, 128, 10, 10, ss, X4, 5, 5, 128, 1664);
  gemm_bt<2><<<26, 256, 0, stream>>>(X4, 1152, Wc4, 1152, C4, nullptr, 256, bc4, 36, 2);

  bn_partial<<<dim3(256, BN_S), 256, 0, stream>>>(C4, 256, 1600, bnp);
  bn_final<<<1, 256, 0, stream>>>(bnp, g4, be4, ss, 256, 1600);
  obj_from_c4<<<(1664 * 256 + 255) / 256, 256, 0, stream>>>(C4, ss, obj);

  // ---- MLP packs ----
  pack_w1<<<2048, 256, 0, stream>>>(gw1, W1a, W1b);
  pack_wbig<<<16384, 256, 0, stream>>>(gw2, Wp2);
  pack_wbig<<<16384, 256, 0, stream>>>(gw3, Wp3);
  pack_wbig<<<16384, 256, 0, stream>>>(gw4, Wp4);
  pack_bias3<<<8, 256, 0, stream>>>(gb2, gb3, gb4, bp);
  q_build<<<512, 256, 0, stream>>>(qst, gw1, gb1, Q);

  // ---- layer-1 decomposition GEMMs ----
  gemm_bt<0><<<13 * 16, 256, 0, stream>>>(obj, 256, W1a, 256, Afull, nullptr, 2048, nullptr, 8, 16);
  gemm_bt<0><<<13 * 16, 256, 0, stream>>>(obj, 256, W1b, 256, Bfull, nullptr, 2048, nullptr, 8, 16);

  // ---- chunked g-MLP with 256^2 counted-vmcnt GEMM ----
  int NC = 64 / CHI;
  int mtiles = (int)(Mp / 256);
  for (int c = 0; c < NC; c++) {
    int c0 = c * CHI;
    int nrows = CHI * 625;
    h1_build<<<(unsigned)Mp, 256, 0, stream>>>(Afull, Bfull, Q, h0, c0, nrows);
    gemm256<<<mtiles * 8, 512, 0, stream>>>(h0, Wp2, h1b, bp, 32);
    gemm256<<<mtiles * 8, 512, 0, stream>>>(h1b, Wp3, h0, bp + 2048, 32);
    gemm256<<<mtiles * 8, 512, 0, stream>>>(h0, Wp4, h1b, bp + 4096, 32);
    reduce_part<<<dim3(CHI, 5), 256, 0, stream>>>(h1b, rpart, CHI);
    reduce_fin<<<(CHI * 2048 + 255) / 256, 256, 0, stream>>>(rpart, xg, c0, CHI);
  }

  // ---- f MLP ----
  {
    int nthreads;
    nthreads = 64 * 1000 * 64;
    f_layer<<<(nthreads + 255) / 256, 256, 0, stream>>>(xg, 2048, 2000, fw1, fb1, xf1, 1024, 1000, 1.f / 625.f, 1);
    nthreads = 64 * 500 * 64;
    f_layer<<<(nthreads + 255) / 256, 256, 0, stream>>>(xf1, 1024, 1000, fw2, fb2, xf2, 512, 500, 1.f, 1);
    nthreads = 64 * 100 * 64;
    f_layer<<<(nthreads + 255) / 256, 256, 0, stream>>>(xf2, 512, 500, fw3, fb3, xf3, 128, 100, 1.f, 1);
    nthreads = 64 * 10 * 64;
    f_layer<<<(nthreads + 255) / 256, 256, 0, stream>>>(xf3, 128, 100, fw4, fb4, xf4, 16, 10, 1.f, 0);
  }
  lsm_kernel<<<1, 64, 0, stream>>>(xf4, out);
}

// Round 4
// 1696.504 us; speedup vs baseline: 2.0505x; 1.0973x over previous
//
#include <hip/hip_runtime.h>

typedef unsigned short u16;
typedef unsigned int u32;
typedef __attribute__((ext_vector_type(8))) short bf16x8;
typedef __attribute__((ext_vector_type(4))) float f32x4;

#define BN_EPS 1e-5f
#define BN_S 16

__device__ __forceinline__ float bf2f(u16 u) {
  union { unsigned u; float f; } x; x.u = ((unsigned)u) << 16; return x.f;
}
__device__ __forceinline__ u16 f2bf(float f) {
  union { float f; unsigned u; } x; x.f = f;
  unsigned r = x.u + 0x7FFFu + ((x.u >> 16) & 1u);
  return (u16)(r >> 16);
}

// ---------------- conv1: direct, NHWC output [64*38*38][32] fp32 ----------------
__global__ void conv1_nhwc(const float* __restrict__ img, const float* __restrict__ w,
                           const float* __restrict__ b, float* __restrict__ C1) {
  int idx = blockIdx.x * blockDim.x + threadIdx.x;
  if (idx >= 92416 * 32) return;
  int co = idx & 31; int row = idx >> 5;
  int wo = row % 38; int t = row / 38;
  int ho = t % 38; int n = t / 38;
  int hi0 = ho * 2 - 1, wi0 = wo * 2 - 1;
  float acc = b[co];
  const float* wp = w + co * 27;
#pragma unroll
  for (int ci = 0; ci < 3; ci++) {
    const float* ip = img + ((size_t)(n * 3 + ci) * 75) * 75;
    const float* wc = wp + ci * 9;
#pragma unroll
    for (int kh = 0; kh < 3; kh++) {
      int hi = hi0 + kh;
      if (hi < 0 || hi >= 75) continue;
#pragma unroll
      for (int kw = 0; kw < 3; kw++) {
        int wi = wi0 + kw;
        if (wi < 0 || wi >= 75) continue;
        acc += ip[hi * 75 + wi] * wc[kh * 3 + kw];
      }
    }
  }
  C1[idx] = acc;
}

// ---------------- BN column-stats (deterministic 2-stage) ----------------
__global__ void bn_partial(const float* __restrict__ C, int ldc, int M,
                           float* __restrict__ part) {
  int c = blockIdx.x; int s = blockIdx.y; int t = threadIdx.x;
  int rowsPer = (M + BN_S - 1) / BN_S;
  int r0 = s * rowsPer; int r1 = r0 + rowsPer; if (r1 > M) r1 = M;
  float s1 = 0.f, s2 = 0.f;
  for (int r = r0 + t; r < r1; r += 256) {
    float v = C[(size_t)r * ldc + c]; s1 += v; s2 += v * v;
  }
  __shared__ float l1[256], l2[256];
  l1[t] = s1; l2[t] = s2; __syncthreads();
  for (int off = 128; off > 0; off >>= 1) {
    if (t < off) { l1[t] += l1[t + off]; l2[t] += l2[t + off]; }
    __syncthreads();
  }
  if (t == 0) { part[s * 512 + c] = l1[0]; part[s * 512 + 256 + c] = l2[0]; }
}

__global__ void bn_final(const float* __restrict__ part, const float* __restrict__ gamma,
                         const float* __restrict__ beta, float* __restrict__ ss,
                         int C, int M) {
  int c = threadIdx.x;
  if (c >= C) { if (c < 256) { ss[c] = 0.f; ss[256 + c] = 0.f; } return; }
  float s1 = 0.f, s2 = 0.f;
#pragma unroll
  for (int s = 0; s < BN_S; s++) { s1 += part[s * 512 + c]; s2 += part[s * 512 + 256 + c]; }
  float mu = s1 / M;
  float var = s2 / M - mu * mu;
  float sc = gamma[c] * rsqrtf(var + BN_EPS);
  ss[c] = sc; ss[256 + c] = beta[c] - mu * sc;
}

// ---------------- fused BN+ReLU + im2col -> bf16 X[row][tap*Ci+ci] ----------------
__global__ void bnrelu_im2col(const float* __restrict__ Cprev, int ldprev, int Hp, int Wp,
                              const float* __restrict__ ss, u16* __restrict__ X,
                              int Ho, int Wo, int Ci, int Mp) {
  int civ4 = Ci >> 2;
  int idx = blockIdx.x * blockDim.x + threadIdx.x;
  int total = Mp * 9 * civ4;
  if (idx >= total) return;
  int cv = idx % civ4; int t2 = idx / civ4;
  int tap = t2 % 9; int row = t2 / 9;
  int K = 9 * Ci;
  u16* dst = X + (size_t)row * K + tap * Ci + cv * 4;
  int HW = Ho * Wo;
  int Mvalid = 64 * HW;
  ushort4 o4; o4.x = 0; o4.y = 0; o4.z = 0; o4.w = 0;
  if (row < Mvalid) {
    int wo = row % Wo; int t = row / Wo;
    int ho = t % Ho; int n = t / Ho;
    int kh = tap / 3, kw = tap % 3;
    int hi = ho * 2 - 1 + kh, wi = wo * 2 - 1 + kw;
    if (hi >= 0 && hi < Hp && wi >= 0 && wi < Wp) {
      const float* src = Cprev + ((size_t)((n * Hp + hi) * Wp + wi)) * ldprev + cv * 4;
      float4 v = *(const float4*)src;
      int c0 = cv * 4;
      float a;
      a = v.x * ss[c0 + 0] + ss[256 + c0 + 0]; o4.x = f2bf(a > 0.f ? a : 0.f);
      a = v.y * ss[c0 + 1] + ss[256 + c0 + 1]; o4.y = f2bf(a > 0.f ? a : 0.f);
      a = v.z * ss[c0 + 2] + ss[256 + c0 + 2]; o4.z = f2bf(a > 0.f ? a : 0.f);
      a = v.w * ss[c0 + 3] + ss[256 + c0 + 3]; o4.w = f2bf(a > 0.f ? a : 0.f);
    }
  }
  *(ushort4*)dst = o4;
}

// ---------------- conv weight pack ----------------
__global__ void pack_convw(const float* __restrict__ w, u16* __restrict__ Wp,
                           int Co, int Ci, int Cop) {
  int K = 9 * Ci;
  int idx = blockIdx.x * blockDim.x + threadIdx.x;
  if (idx >= Cop * K) return;
  int k = idx % K; int co = idx / K;
  int tap = k / Ci; int ci = k % Ci;
  float v = (co < Co) ? w[((size_t)co * Ci + ci) * 9 + tap] : 0.f;
  Wp[idx] = f2bf(v);
}

__global__ void pad_bias(const float* __restrict__ b, float* __restrict__ bc, int Co, int Cop) {
  int i = blockIdx.x * blockDim.x + threadIdx.x;
  if (i < Cop) bc[i] = (i < Co) ? b[i] : 0.f;
}

// ---------------- obj pack from C4 with BN+ReLU ----------------
__global__ void obj_from_c4(const float* __restrict__ C4, const float* __restrict__ ss,
                            u16* __restrict__ obj) {
  int idx = blockIdx.x * blockDim.x + threadIdx.x;
  if (idx >= 1664 * 256) return;
  int c = idx & 255; int row = idx >> 8;
  float v = 0.f;
  if (row < 1600) {
    float x = C4[(size_t)row * 256 + c];
    x = x * ss[c] + ss[256 + c];
    v = x > 0.f ? x : 0.f;
  }
  obj[idx] = f2bf(v);
}

// ---------------- MLP weight packs ----------------
__global__ void pack_w1(const float* __restrict__ gw1, u16* __restrict__ W1a, u16* __restrict__ W1b) {
  int idx = blockIdx.x * blockDim.x + threadIdx.x;
  if (idx >= 2048 * 256) return;
  int k = idx & 255, n = idx >> 8;
  float a = 0.f, b = 0.f;
  if (n < 2000) { a = gw1[(size_t)n * 523 + k]; b = gw1[(size_t)n * 523 + 256 + k]; }
  W1a[idx] = f2bf(a); W1b[idx] = f2bf(b);
}

__global__ void pack_wbig(const float* __restrict__ gw, u16* __restrict__ Wp) {
  int idx = blockIdx.x * blockDim.x + threadIdx.x;
  if (idx >= 2048 * 2048) return;
  int k = idx & 2047, n = idx >> 11;
  float v = (n < 2000 && k < 2000) ? gw[(size_t)n * 2000 + k] : 0.f;
  Wp[idx] = f2bf(v);
}

__global__ void pack_bias3(const float* __restrict__ b2, const float* __restrict__ b3,
                           const float* __restrict__ b4, float* __restrict__ bp) {
  int i = blockIdx.x * blockDim.x + threadIdx.x;
  if (i >= 2048) return;
  bp[i]        = (i < 2000) ? b2[i] : 0.f;
  bp[2048 + i] = (i < 2000) ? b3[i] : 0.f;
  bp[4096 + i] = (i < 2000) ? b4[i] : 0.f;
}

// ---------------- Q[b][o] = gb1[o] + qst[b] . gw1[o][512:523] ----------------
__global__ void q_build(const float* __restrict__ qst, const float* __restrict__ gw1,
                        const float* __restrict__ gb1, float* __restrict__ Q) {
  int idx = blockIdx.x * blockDim.x + threadIdx.x;
  if (idx >= 64 * 2048) return;
  int o = idx & 2047, b = idx >> 11;
  float v = 0.f;
  if (o < 2000) {
    v = gb1[o];
    const float* w = gw1 + (size_t)o * 523 + 512;
    const float* q = qst + b * 11;
#pragma unroll
    for (int k = 0; k < 11; k++) v += q[k] * w[k];
  }
  Q[idx] = v;
}

// ---------------- global->LDS async ----------------
typedef const __attribute__((address_space(1))) u32* gas1;
typedef __attribute__((address_space(3))) u32* las3;
__device__ __forceinline__ void gld16(const void* g, void* l) {
  __builtin_amdgcn_global_load_lds((gas1)g, (las3)l, 16, 0, 0);
}

// ---------------- 128^2 bf16 MFMA GEMM (small/medium shapes) ----------------
// EPI 0: fp32 store raw; EPI 2: fp32 store acc+bias
template <int EPI>
__global__ __launch_bounds__(256) void gemm_bt(
    const u16* __restrict__ A, int lda,
    const u16* __restrict__ W, int ldb,
    float* __restrict__ Cf, u16* __restrict__ Cb, int ldc,
    const float* __restrict__ bias, int KT, int NTN) {
  __shared__ __align__(16) char lds[32768];
  int bid = blockIdx.x;
  int wg;
  if ((gridDim.x & 7) == 0) {
    int cpx = gridDim.x >> 3;
    wg = (bid & 7) * cpx + (bid >> 3);
  } else {
    wg = bid;
  }
  int mt = wg / NTN, nt = wg % NTN;
  int tid = threadIdx.x;
  int wave = tid >> 6, lane = tid & 63;
  int r = lane & 15, g = lane >> 4;
  int wr = wave >> 1, wc = wave & 1;

  const u16* Asrc = A + (size_t)(mt * 128 + wave * 32 + r) * lda + g * 8;
  const u16* Wsrc = W + (size_t)(nt * 128 + wave * 32 + r) * ldb + g * 8;

  f32x4 acc[4][4];
#pragma unroll
  for (int i = 0; i < 4; i++)
#pragma unroll
    for (int j = 0; j < 4; j++) acc[i][j] = (f32x4){0.f, 0.f, 0.f, 0.f};

  {
    char* Al = lds; char* Wl = lds + 8192;
    gld16(Asrc, Al + wave * 2048);
    gld16(Asrc + (size_t)16 * lda, Al + wave * 2048 + 1024);
    gld16(Wsrc, Wl + wave * 2048);
    gld16(Wsrc + (size_t)16 * ldb, Wl + wave * 2048 + 1024);
  }
  __syncthreads();

  int buf = 0;
  for (int kt = 0; kt < KT; kt++) {
    if (kt + 1 < KT) {
      int k0 = (kt + 1) * 32;
      char* Al = lds + (buf ^ 1) * 16384; char* Wl = Al + 8192;
      gld16(Asrc + k0, Al + wave * 2048);
      gld16(Asrc + k0 + (size_t)16 * lda, Al + wave * 2048 + 1024);
      gld16(Wsrc + k0, Wl + wave * 2048);
      gld16(Wsrc + k0 + (size_t)16 * ldb, Wl + wave * 2048 + 1024);
    }
    char* Al = lds + buf * 16384; char* Wl = Al + 8192;
    bf16x8 a[4], w[4];
#pragma unroll
    for (int i = 0; i < 4; i++) a[i] = *(const bf16x8*)(Al + (wr * 4 + i) * 1024 + lane * 16);
#pragma unroll
    for (int j = 0; j < 4; j++) w[j] = *(const bf16x8*)(Wl + (wc * 4 + j) * 1024 + lane * 16);
#pragma unroll
    for (int i = 0; i < 4; i++)
#pragma unroll
      for (int j = 0; j < 4; j++)
        acc[i][j] = __builtin_amdgcn_mfma_f32_16x16x32_bf16(a[i], w[j], acc[i][j], 0, 0, 0);
    __syncthreads();
    buf ^= 1;
  }

  int rowb = mt * 128 + wr * 64 + (lane >> 4) * 4;
  int colb = nt * 128 + wc * 64 + (lane & 15);
#pragma unroll
  for (int i = 0; i < 4; i++) {
#pragma unroll
    for (int j = 0; j < 4; j++) {
      int col = colb + j * 16;
      float bv = (EPI != 0) ? bias[col] : 0.f;
#pragma unroll
      for (int q = 0; q < 4; q++) {
        int row = rowb + i * 16 + q;
        float v = acc[i][j][q];
        if (EPI == 2) {
          Cf[(size_t)row * ldc + col] = v + bv;
        } else {
          Cf[(size_t)row * ldc + col] = v;
        }
      }
    }
  }
}

// ---------------- 256^2 multi-phase counted-vmcnt bf16 GEMM ----------------
// C[m][n] = relu(sum_k A[m][k]*W[n][k] + bias[n]) -> bf16. lda=ldb=ldc=2048.
// BK=32, 4-deep circular LDS (4 x 32KB), 2 phases/K-tile, stages target tile
// t+3 (distance ~6 phases), boundary vmcnt(8)/(4)/(0), setprio around MFMA.
template <int NT>
__global__ __launch_bounds__(512, 2) void gemm256(
    const u16* __restrict__ A, const u16* __restrict__ W,
    u16* __restrict__ Cb, const float* __restrict__ bias) {
  __shared__ __align__(16) char lds[131072];
  int bid = blockIdx.x;
  int cpx = gridDim.x >> 3;                 // grid = mtiles*8, always %8==0
  int wg = (bid & 7) * cpx + (bid >> 3);
  int mt = wg >> 3, nt = wg & 3 ? wg & 7 : wg & 7;  // NTN=8 fixed
  nt = wg & 7; mt = wg >> 3;
  int tid = threadIdx.x;
  int wave = tid >> 6, lane = tid & 63;
  int r = lane & 15, g = lane >> 4;
  int wr = wave >> 2, wc = wave & 3;
  const int lda = 2048;

  // staging pointers: chunk sub = wave*2 + p, rows sub*16 + r, k = g*8
  const u16* gA0 = A + (size_t)(mt * 256 + (wave * 2 + 0) * 16 + r) * lda + g * 8;
  const u16* gA1 = A + (size_t)(mt * 256 + (wave * 2 + 1) * 16 + r) * lda + g * 8;
  const u16* gB0 = W + (size_t)(nt * 256 + (wave * 2 + 0) * 16 + r) * lda + g * 8;
  const u16* gB1 = W + (size_t)(nt * 256 + (wave * 2 + 1) * 16 + r) * lda + g * 8;
  int subA = (wave * 2) * 1024;

  f32x4 acc[8][4];
#pragma unroll
  for (int i = 0; i < 8; i++)
#pragma unroll
    for (int j = 0; j < 4; j++) acc[i][j] = (f32x4){0.f, 0.f, 0.f, 0.f};

  // prologue: stage tiles 0,1,2 into bufs 0,1,2
#pragma unroll
  for (int pt = 0; pt < 3; pt++) {
    if (pt < NT) {
      char* sb = lds + pt * 32768;
      gld16(gA0, sb + subA);
      gld16(gB0, sb + 16384 + subA);
      gld16(gA1, sb + subA + 1024);
      gld16(gB1, sb + 16384 + subA + 1024);
      gA0 += 32; gA1 += 32; gB0 += 32; gB1 += 32;
    }
  }
  asm volatile("s_waitcnt vmcnt(8)" ::: "memory");   // tile 0 landed (1,2 in flight)
  __builtin_amdgcn_sched_barrier(0);
  __builtin_amdgcn_s_barrier();

  for (int t = 0; t < NT; t++) {
    const char* base = lds + (t & 3) * 32768;
    char* sbase = lds + ((t + 3) & 3) * 32768;
    bool do_stage = (t + 3 < NT);

    // ---- phase 0: i = 0..3, load all b-frags ----
    bf16x8 a[4], b[4];
#pragma unroll
    for (int i = 0; i < 4; i++)
      a[i] = *(const bf16x8*)(base + (wr * 8 + i) * 1024 + lane * 16);
#pragma unroll
    for (int j = 0; j < 4; j++)
      b[j] = *(const bf16x8*)(base + 16384 + (wc * 4 + j) * 1024 + lane * 16);
    if (do_stage) {
      gld16(gA0, sbase + subA);
      gld16(gB0, sbase + 16384 + subA);
      gA0 += 32; gB0 += 32;
    }
    __builtin_amdgcn_sched_barrier(0);
    __builtin_amdgcn_s_barrier();
    asm volatile("s_waitcnt lgkmcnt(0)" ::: "memory");
    __builtin_amdgcn_sched_barrier(0);
    __builtin_amdgcn_s_setprio(1);
#pragma unroll
    for (int i = 0; i < 4; i++)
#pragma unroll
      for (int j = 0; j < 4; j++)
        acc[i][j] = __builtin_amdgcn_mfma_f32_16x16x32_bf16(a[i], b[j], acc[i][j], 0, 0, 0);
    __builtin_amdgcn_s_setprio(0);
    __builtin_amdgcn_sched_barrier(0);
    __builtin_amdgcn_s_barrier();

    // ---- phase 1: i = 4..7 ----
#pragma unroll
    for (int i = 0; i < 4; i++)
      a[i] = *(const bf16x8*)(base + (wr * 8 + 4 + i) * 1024 + lane * 16);
    if (do_stage) {
      gld16(gA1, sbase + subA + 1024);
      gld16(gB1, sbase + 16384 + subA + 1024);
      gA1 += 32; gB1 += 32;
    }
    __builtin_amdgcn_sched_barrier(0);
    __builtin_amdgcn_s_barrier();
    asm volatile("s_waitcnt lgkmcnt(0)" ::: "memory");
    __builtin_amdgcn_sched_barrier(0);
    __builtin_amdgcn_s_setprio(1);
#pragma unroll
    for (int i = 0; i < 4; i++)
#pragma unroll
      for (int j = 0; j < 4; j++)
        acc[i + 4][j] = __builtin_amdgcn_mfma_f32_16x16x32_bf16(a[i], b[j], acc[i + 4][j], 0, 0, 0);
    __builtin_amdgcn_s_setprio(0);

    // boundary wait for next tile (counted; only drains at the very end)
    int rem = NT - 1 - t;
    if (rem >= 3)      { asm volatile("s_waitcnt vmcnt(8)" ::: "memory"); }
    else if (rem == 2) { asm volatile("s_waitcnt vmcnt(4)" ::: "memory"); }
    else if (rem == 1) { asm volatile("s_waitcnt vmcnt(0)" ::: "memory"); }
    __builtin_amdgcn_sched_barrier(0);
    __builtin_amdgcn_s_barrier();
  }

  // epilogue: frag D layout col=lane&15, row=(lane>>4)*4+q
  int rowb = mt * 256 + wr * 128 + g * 4;
  int colb = nt * 256 + wc * 64 + r;
#pragma unroll
  for (int i = 0; i < 8; i++) {
#pragma unroll
    for (int j = 0; j < 4; j++) {
      int col = colb + j * 16;
      float bv = bias[col];
#pragma unroll
      for (int q = 0; q < 4; q++) {
        int row = rowb + i * 16 + q;
        float v = acc[i][j][q] + bv;
        v = v > 0.f ? v : 0.f;
        Cb[(size_t)row * 2048 + col] = f2bf(v);
      }
    }
  }
}

// ---------------- h1 = relu(A_i + B_j + Q_b), bf16 ----------------
__global__ void h1_build(const float* __restrict__ Afull, const float* __restrict__ Bfull,
                         const float* __restrict__ Q, u16* __restrict__ h1,
                         int c0, int nrows) {
  int row = blockIdx.x;
  int t = threadIdx.x;
  u16* dst = h1 + (size_t)row * 2048;
  if (row >= nrows) {
#pragma unroll
    for (int it = 0; it < 2; it++) {
      int o = it * 1024 + t * 4;
      ushort4 z; z.x = 0; z.y = 0; z.z = 0; z.w = 0;
      *(ushort4*)(dst + o) = z;
    }
    return;
  }
  int b_local = row / 625; int rem = row % 625;
  int i = rem / 25, j = rem % 25;
  int b = c0 + b_local;
  const float* Ap = Afull + (size_t)(b * 25 + i) * 2048;
  const float* Bp = Bfull + (size_t)(b * 25 + j) * 2048;
  const float* Qp = Q + (size_t)b * 2048;
#pragma unroll
  for (int it = 0; it < 2; it++) {
    int o = it * 1024 + t * 4;
    float4 av = *(const float4*)(Ap + o);
    float4 bv = *(const float4*)(Bp + o);
    float4 qv = *(const float4*)(Qp + o);
    ushort4 outv;
    float v;
    v = av.x + bv.x + qv.x; outv.x = f2bf(v > 0.f ? v : 0.f);
    v = av.y + bv.y + qv.y; outv.y = f2bf(v > 0.f ? v : 0.f);
    v = av.z + bv.z + qv.z; outv.z = f2bf(v > 0.f ? v : 0.f);
    v = av.w + bv.w + qv.w; outv.w = f2bf(v > 0.f ? v : 0.f);
    *(ushort4*)(dst + o) = outv;
  }
}

// ---------------- pair-sum reduce, deterministic 2-stage ----------------
__global__ void reduce_part(const u16* __restrict__ h4, float* __restrict__ part, int CHI) {
  int bl = blockIdx.x; int s = blockIdx.y; int t = threadIdx.x;
  int k0 = s * 125, k1 = k0 + 125;
  const u16* base = h4 + ((size_t)bl * 625) * 2048 + t * 8;
  float acc0 = 0.f, acc1 = 0.f, acc2 = 0.f, acc3 = 0.f;
  float acc4 = 0.f, acc5 = 0.f, acc6 = 0.f, acc7 = 0.f;
  for (int k = k0; k < k1; k++) {
    uint4 u = *(const uint4*)(base + (size_t)k * 2048);
    acc0 += bf2f((u16)(u.x & 0xffff)); acc1 += bf2f((u16)(u.x >> 16));
    acc2 += bf2f((u16)(u.y & 0xffff)); acc3 += bf2f((u16)(u.y >> 16));
    acc4 += bf2f((u16)(u.z & 0xffff)); acc5 += bf2f((u16)(u.z >> 16));
    acc6 += bf2f((u16)(u.w & 0xffff)); acc7 += bf2f((u16)(u.w >> 16));
  }
  float* dst = part + (((size_t)s * CHI + bl) * 2048) + t * 8;
  dst[0] = acc0; dst[1] = acc1; dst[2] = acc2; dst[3] = acc3;
  dst[4] = acc4; dst[5] = acc5; dst[6] = acc6; dst[7] = acc7;
}

__global__ void reduce_fin(const float* __restrict__ part, float* __restrict__ xg,
                           int c0, int CHI) {
  int idx = blockIdx.x * blockDim.x + threadIdx.x;
  if (idx >= CHI * 2048) return;
  int bl = idx >> 11; int o = idx & 2047;
  float sv = 0.f;
#pragma unroll
  for (int st = 0; st < 5; st++) sv += part[((size_t)st * CHI + bl) * 2048 + o];
  xg[(size_t)(c0 + bl) * 2048 + o] = sv;
}

// ---------------- f MLP: warp per output, fp32 ----------------
__global__ void f_layer(const float* __restrict__ x, int ldx, int Kin,
                        const float* __restrict__ Wf, const float* __restrict__ bf_,
                        float* __restrict__ y, int ldy, int Nout, float scale, int relu) {
  int gwid = (blockIdx.x * blockDim.x + threadIdx.x) >> 6;
  int lane = threadIdx.x & 63;
  if (gwid >= 64 * Nout) return;
  int b = gwid / Nout, o = gwid % Nout;
  const float* xp = x + (size_t)b * ldx;
  const float* wp = Wf + (size_t)o * Kin;
  float s = 0.f;
  for (int k = lane; k < Kin; k += 64) s += xp[k] * wp[k];
  for (int off = 32; off > 0; off >>= 1) s += __shfl_down(s, off);
  if (lane == 0) {
    float v = s * scale + bf_[o];
    if (relu) v = v > 0.f ? v : 0.f;
    y[(size_t)b * ldy + o] = v;
  }
}

__global__ void lsm_kernel(const float* __restrict__ xf4, float* __restrict__ out) {
  int b = blockIdx.x * blockDim.x + threadIdx.x;
  if (b >= 64) return;
  const float* x = xf4 + b * 16;
  float m = x[0];
  for (int i = 1; i < 10; i++) m = fmaxf(m, x[i]);
  float s = 0.f;
  for (int i = 0; i < 10; i++) s += expf(x[i] - m);
  float ls = logf(s);
  for (int i = 0; i < 10; i++) out[b * 10 + i] = x[i] - m - ls;
}

// ---------------- host ----------------
extern "C" void kernel_launch(void* const* d_in, const int* in_sizes, int n_in,
                              void* d_out, int out_size, void* d_ws, size_t ws_size,
                              hipStream_t stream) {
  const float* img = (const float*)d_in[0];
  const float* qst = (const float*)d_in[1];
  const float* w1 = (const float*)d_in[2];  const float* b1 = (const float*)d_in[3];
  const float* w2 = (const float*)d_in[4];  const float* b2 = (const float*)d_in[5];
  const float* w3 = (const float*)d_in[6];  const float* b3 = (const float*)d_in[7];
  const float* w4 = (const float*)d_in[8];  const float* b4 = (const float*)d_in[9];
  const float* g1 = (const float*)d_in[10]; const float* be1 = (const float*)d_in[11];
  const float* g2 = (const float*)d_in[12]; const float* be2 = (const float*)d_in[13];
  const float* g3 = (const float*)d_in[14]; const float* be3 = (const float*)d_in[15];
  const float* g4 = (const float*)d_in[16]; const float* be4 = (const float*)d_in[17];
  const float* gw1 = (const float*)d_in[18]; const float* gb1 = (const float*)d_in[19];
  const float* gw2 = (const float*)d_in[20]; const float* gb2 = (const float*)d_in[21];
  const float* gw3 = (const float*)d_in[22]; const float* gb3 = (const float*)d_in[23];
  const float* gw4 = (const float*)d_in[24]; const float* gb4 = (const float*)d_in[25];
  const float* fw1 = (const float*)d_in[26]; const float* fb1 = (const float*)d_in[27];
  const float* fw2 = (const float*)d_in[28]; const float* fb2 = (const float*)d_in[29];
  const float* fw3 = (const float*)d_in[30]; const float* fb3 = (const float*)d_in[31];
  const float* fw4 = (const float*)d_in[32]; const float* fb4 = (const float*)d_in[33];
  float* out = (float*)d_out;

  // ---- persistent region ----
  char* P = (char*)d_ws;
  auto alloc = [&](size_t bytes) -> char* {
    char* r = P; P += (bytes + 255) & ~(size_t)255; return r;
  };
  u16* Wp2 = (u16*)alloc(2048ull * 2048 * 2);
  u16* Wp3 = (u16*)alloc(2048ull * 2048 * 2);
  u16* Wp4 = (u16*)alloc(2048ull * 2048 * 2);
  float* Afull = (float*)alloc(1664ull * 2048 * 4);
  float* Bfull = (float*)alloc(1664ull * 2048 * 4);
  float* Q = (float*)alloc(64ull * 2048 * 4);
  float* bp = (float*)alloc(3ull * 2048 * 4);
  u16* W1a = (u16*)alloc(2048ull * 256 * 2);
  u16* W1b = (u16*)alloc(2048ull * 256 * 2);
  u16* obj = (u16*)alloc(1664ull * 256 * 2);
  float* xg = (float*)alloc(64ull * 2048 * 4);
  float* xf1 = (float*)alloc(64ull * 1024 * 4);
  float* xf2 = (float*)alloc(64ull * 512 * 4);
  float* xf3 = (float*)alloc(64ull * 128 * 4);
  float* xf4 = (float*)alloc(64ull * 16 * 4);

  // ---- scratch region (conv buffers and h buffers alias each other) ----
  char* scratch = P;
  size_t scratch_avail = ws_size - (size_t)(scratch - (char*)d_ws);
  auto salloc = [&](char*& sp, size_t bytes) -> char* {
    char* r = sp; sp += (bytes + 255) & ~(size_t)255; return r;
  };
  char* sp = scratch;
  float* C1 = (float*)salloc(sp, 92416ull * 32 * 4);
  u16*   X2 = (u16*)salloc(sp, 23168ull * 288 * 2);
  float* C2 = (float*)salloc(sp, 23168ull * 128 * 4);
  u16*   X3 = (u16*)salloc(sp, 6400ull * 576 * 2);
  float* C3 = (float*)salloc(sp, 6400ull * 128 * 4);
  u16*   X4 = (u16*)salloc(sp, 1664ull * 1152 * 2);
  float* C4 = (float*)salloc(sp, 1664ull * 256 * 4);
  u16*  Wc2 = (u16*)salloc(sp, 128ull * 288 * 2);
  u16*  Wc3 = (u16*)salloc(sp, 128ull * 576 * 2);
  u16*  Wc4 = (u16*)salloc(sp, 256ull * 1152 * 2);
  float* bc2 = (float*)salloc(sp, 128 * 4);
  float* bc3 = (float*)salloc(sp, 128 * 4);
  float* bc4 = (float*)salloc(sp, 256 * 4);
  float* bnp = (float*)salloc(sp, BN_S * 512 * 4);
  float* ss  = (float*)salloc(sp, 512 * 4);

  // h-phase buffers: pick largest CHI whose buffers fit scratch
  int cands[7] = {64, 32, 16, 8, 4, 2, 1};
  int CHI = 1;
  size_t Mp = 768;
  for (int ci = 0; ci < 7; ci++) {
    size_t mp = (((size_t)cands[ci] * 625 + 255) / 256) * 256;
    size_t hb = (mp * 2048 * 2 + 255) & ~(size_t)255;
    size_t rp = ((size_t)5 * cands[ci] * 2048 * 4 + 255) & ~(size_t)255;
    if (2 * hb + rp <= scratch_avail) {
      CHI = cands[ci]; Mp = mp; break;
    }
  }
  char* hp = scratch;
  u16* h0  = (u16*)salloc(hp, Mp * 2048 * 2);
  u16* h1b = (u16*)salloc(hp, Mp * 2048 * 2);
  float* rpart = (float*)salloc(hp, (size_t)5 * CHI * 2048 * 4);

  // ---- conv weight/bias packs ----
  pack_convw<<<(128 * 288 + 255) / 256, 256, 0, stream>>>(w2, Wc2, 64, 32, 128);
  pack_convw<<<(128 * 576 + 255) / 256, 256, 0, stream>>>(w3, Wc3, 128, 64, 128);
  pack_convw<<<(256 * 1152 + 255) / 256, 256, 0, stream>>>(w4, Wc4, 256, 128, 256);
  pad_bias<<<1, 256, 0, stream>>>(b2, bc2, 64, 128);
  pad_bias<<<1, 256, 0, stream>>>(b3, bc3, 128, 128);
  pad_bias<<<1, 256, 0, stream>>>(b4, bc4, 256, 256);

  // ---- conv stack ----
  conv1_nhwc<<<(92416 * 32 + 255) / 256, 256, 0, stream>>>(img, w1, b1, C1);
  bn_partial<<<dim3(32, BN_S), 256, 0, stream>>>(C1, 32, 92416, bnp);
  bn_final<<<1, 256, 0, stream>>>(bnp, g1, be1, ss, 32, 92416);
  bnrelu_im2col<<<(23168 * 9 * 8 + 255) / 256, 256, 0, stream>>>(C1, 32, 38, 38, ss, X2, 19, 19, 32, 23168);
  gemm_bt<2><<<181, 256, 0, stream>>>(X2, 288, Wc2, 288, C2, nullptr, 128, bc2, 9, 1);

  bn_partial<<<dim3(64, BN_S), 256, 0, stream>>>(C2, 128, 23104, bnp);
  bn_final<<<1, 256, 0, stream>>>(bnp, g2, be2, ss, 64, 23104);
  bnrelu_im2col<<<(6400 * 9 * 16 + 255) / 256, 256, 0, stream>>>(C2, 128, 19, 19, ss, X3, 10, 10, 64, 6400);
  gemm_bt<2><<<50, 256, 0, stream>>>(X3, 576, Wc3, 576, C3, nullptr, 128, bc3, 18, 1);

  bn_partial<<<dim3(128, BN_S), 256, 0, stream>>>(C3, 128, 6400, bnp);
  bn_final<<<1, 256, 0, stream>>>(bnp, g3, be3, ss, 128, 6400);
  bnrelu_im2col<<<(1664 * 9 * 32 + 255) / 256, 256, 0, stream>>>(C3, 128, 10, 10, ss, X4, 5, 5, 128, 1664);
  gemm_bt<2><<<26, 256, 0, stream>>>(X4, 1152, Wc4, 1152, C4, nullptr, 256, bc4, 36, 2);

  bn_partial<<<dim3(256, BN_S), 256, 0, stream>>>(C4, 256, 1600, bnp);
  bn_final<<<1, 256, 0, stream>>>(bnp, g4, be4, ss, 256, 1600);
  obj_from_c4<<<(1664 * 256 + 255) / 256, 256, 0, stream>>>(C4, ss, obj);

  // ---- MLP packs ----
  pack_w1<<<2048, 256, 0, stream>>>(gw1, W1a, W1b);
  pack_wbig<<<16384, 256, 0, stream>>>(gw2, Wp2);
  pack_wbig<<<16384, 256, 0, stream>>>(gw3, Wp3);
  pack_wbig<<<16384, 256, 0, stream>>>(gw4, Wp4);
  pack_bias3<<<8, 256, 0, stream>>>(gb2, gb3, gb4, bp);
  q_build<<<512, 256, 0, stream>>>(qst, gw1, gb1, Q);

  // ---- layer-1 decomposition GEMMs ----
  gemm_bt<0><<<13 * 16, 256, 0, stream>>>(obj, 256, W1a, 256, Afull, nullptr, 2048, nullptr, 8, 16);
  gemm_bt<0><<<13 * 16, 256, 0, stream>>>(obj, 256, W1b, 256, Bfull, nullptr, 2048, nullptr, 8, 16);

  // ---- chunked g-MLP with multi-phase 256^2 GEMM ----
  int NC = 64 / CHI;
  int mtiles = (int)(Mp / 256);
  for (int c = 0; c < NC; c++) {
    int c0 = c * CHI;
    int nrows = CHI * 625;
    h1_build<<<(unsigned)Mp, 256, 0, stream>>>(Afull, Bfull, Q, h0, c0, nrows);
    gemm256<64><<<mtiles * 8, 512, 0, stream>>>(h0, Wp2, h1b, bp);
    gemm256<64><<<mtiles * 8, 512, 0, stream>>>(h1b, Wp3, h0, bp + 2048);
    gemm256<64><<<mtiles * 8, 512, 0, stream>>>(h0, Wp4, h1b, bp + 4096);
    reduce_part<<<dim3(CHI, 5), 256, 0, stream>>>(h1b, rpart, CHI);
    reduce_fin<<<(CHI * 2048 + 255) / 256, 256, 0, stream>>>(rpart, xg, c0, CHI);
  }

  // ---- f MLP ----
  {
    int nthreads;
    nthreads = 64 * 1000 * 64;
    f_layer<<<(nthreads + 255) / 256, 256, 0, stream>>>(xg, 2048, 2000, fw1, fb1, xf1, 1024, 1000, 1.f / 625.f, 1);
    nthreads = 64 * 500 * 64;
    f_layer<<<(nthreads + 255) / 256, 256, 0, stream>>>(xf1, 1024, 1000, fw2, fb2, xf2, 512, 500, 1.f, 1);
    nthreads = 64 * 100 * 64;
    f_layer<<<(nthreads + 255) / 256, 256, 0, stream>>>(xf2, 512, 500, fw3, fb3, xf3, 128, 100, 1.f, 1);
    nthreads = 64 * 10 * 64;
    f_layer<<<(nthreads + 255) / 256, 256, 0, stream>>>(xf3, 128, 100, fw4, fb4, xf4, 16, 10, 1.f, 0);
  }
  lsm_kernel<<<1, 64, 0, stream>>>(xf4, out);
}